// Round 2
// baseline (6596.635 us; speedup 1.0000x reference)
//
#include <hip/hip_runtime.h>

constexpr int NROW = 50000;
constexpr int NCOL = 50000;
constexpr int DH   = 128;

// ---- degree counting (unweighted, per relation) ----
__global__ void deg_count(const int* __restrict__ src, const int* __restrict__ dst,
                          float* __restrict__ cnt_src, float* __restrict__ cnt_dst, int E) {
    int stride = gridDim.x * blockDim.x;
    for (int i = blockIdx.x * blockDim.x + threadIdx.x; i < E; i += stride) {
        atomicAdd(&cnt_src[src[i]], 1.0f);
        atomicAdd(&cnt_dst[dst[i]], 1.0f);
    }
}

// in-place: a = 1/sqrt(max(a,1))
__global__ void rsqrt_clamp(float* __restrict__ a, int n) {
    int stride = gridDim.x * blockDim.x;
    for (int i = blockIdx.x * blockDim.x + threadIdx.x; i < n; i += stride)
        a[i] = 1.0f / sqrtf(fmaxf(a[i], 1.0f));
}

// ---- per-edge combined scale: se[e] = w[e] * rout[src[e]] (reused by both layers) ----
__global__ void edge_scale(const float* __restrict__ w, const int* __restrict__ src,
                           const float* __restrict__ rout, float* __restrict__ se, int E) {
    int stride = gridDim.x * blockDim.x;
    for (int i = blockIdx.x * blockDim.x + threadIdx.x; i < E; i += stride)
        se[i] = w[i] * rout[src[i]];
}

// ---- edge scatter: agg[dst, f4:f4+4] += h[src, f4:f4+4] * se[e], float4 gather ----
template <int D>
__global__ void scatter_add4(const float* __restrict__ h, const int* __restrict__ src,
                             const int* __restrict__ dst, const float* __restrict__ se,
                             float* __restrict__ agg, int E) {
    constexpr int LOGT = (D == 64) ? 4 : 5;      // threads per edge = D/4
    const int total = E << LOGT;
    const int stride = gridDim.x * blockDim.x;
    for (int i = blockIdx.x * blockDim.x + threadIdx.x; i < total; i += stride) {
        const int e  = i >> LOGT;
        const int f4 = (i & ((D / 4) - 1)) << 2;
        const int s = src[e];
        const int d = dst[e];
        const float wv = se[e];
        const float4 hv = *reinterpret_cast<const float4*>(&h[(size_t)s * D + f4]);
        float* ap = &agg[(size_t)d * D + f4];
        atomicAdd(ap + 0, hv.x * wv);
        atomicAdd(ap + 1, hv.y * wv);
        atomicAdd(ap + 2, hv.z * wv);
        atomicAdd(ap + 3, hv.w * wv);
    }
}

// ---- dense epilogue: relu(rin[node] * (agg[node,:] @ W) + b), 8 nodes/iter register-blocked
// MEANSUM: accumulate column means into out[0..127] instead of storing rows.
template <int K, bool MEANSUM>
__global__ void dense_relu_k(const float* __restrict__ agg, const float* __restrict__ rin,
                             const float* __restrict__ W, const float* __restrict__ b,
                             float* __restrict__ out, int n, float invn) {
    constexpr int NB = 8;
    constexpr int LOGK = (K == 64) ? 6 : 7;
    __shared__ float a[NB][K];
    const int t = threadIdx.x;                   // 0..127, one output column each
    const float bias = b[t];
    float acc = 0.f;
    for (int base = blockIdx.x * NB; base < n; base += gridDim.x * NB) {
#pragma unroll
        for (int j = 0; j < NB * K / 128; ++j) { // cooperative LDS stage of 8 agg rows
            int idx = t + j * 128;
            int r = idx >> LOGK, c = idx & (K - 1);
            int node = base + r;
            a[r][c] = (node < n) ? agg[(size_t)node * K + c] : 0.f;
        }
        __syncthreads();
        float s[NB];
#pragma unroll
        for (int r = 0; r < NB; ++r) s[r] = 0.f;
#pragma unroll 4
        for (int k = 0; k < K; ++k) {
            const float wk = W[k * DH + t];      // coalesced; reused 8x
#pragma unroll
            for (int r = 0; r < NB; ++r) s[r] = fmaf(a[r][k], wk, s[r]);
        }
#pragma unroll
        for (int r = 0; r < NB; ++r) {
            const int node = base + r;
            if (node < n) {
                const float v = fmaxf(fmaf(rin[node], s[r], bias), 0.f);
                if (MEANSUM) acc += v;
                else out[(size_t)node * DH + t] = v;
            }
        }
        __syncthreads();
    }
    if (MEANSUM) atomicAdd(&out[t], acc * invn);
}

extern "C" void kernel_launch(void* const* d_in, const int* in_sizes, int n_in,
                              void* d_out, int out_size, void* d_ws, size_t ws_size,
                              hipStream_t stream) {
    const float* feat_row = (const float*)d_in[0];
    const float* feat_col = (const float*)d_in[1];
    const int*   src_rc   = (const int*)d_in[2];
    const int*   dst_rc   = (const int*)d_in[3];
    const float* w_rc     = (const float*)d_in[4];
    const int*   src_cr   = (const int*)d_in[5];
    const int*   dst_cr   = (const int*)d_in[6];
    const float* w_cr     = (const float*)d_in[7];
    const float* W0_rc    = (const float*)d_in[8];
    const float* b0_rc    = (const float*)d_in[9];
    const float* W0_cr    = (const float*)d_in[10];
    const float* b0_cr    = (const float*)d_in[11];
    const float* W1_rc    = (const float*)d_in[12];
    const float* b1_rc    = (const float*)d_in[13];
    const float* W1_cr    = (const float*)d_in[14];
    const float* b1_cr    = (const float*)d_in[15];
    const int E = in_sizes[2];
    float* out = (float*)d_out;

    // workspace layout (fp32), ~113 MB total
    float* ws       = (float*)d_ws;
    float* r_out_rc = ws;                          // NROW
    float* r_in_rc  = ws + NROW;                   // NCOL
    float* r_out_cr = ws + NROW + NCOL;            // NCOL
    float* r_in_cr  = ws + NROW + 2 * NCOL;        // NROW
    float* se_rc    = ws + 200000;                 // E
    float* se_cr    = se_rc + E;                   // E
    float* agg_col  = se_cr + E;                   // NCOL*128
    float* agg_row  = agg_col + (size_t)NCOL * DH;
    float* h_col1   = agg_row + (size_t)NROW * DH;
    float* h_row1   = h_col1  + (size_t)NCOL * DH;

    // degree norms (shared by both layers)
    hipMemsetAsync(ws, 0, 200000 * sizeof(float), stream);
    deg_count<<<1024, 256, 0, stream>>>(src_rc, dst_rc, r_out_rc, r_in_rc, E);
    deg_count<<<1024, 256, 0, stream>>>(src_cr, dst_cr, r_out_cr, r_in_cr, E);
    rsqrt_clamp<<<(200000 + 255) / 256, 256, 0, stream>>>(ws, 200000);

    // per-edge combined scales (reused by both layers)
    edge_scale<<<1024, 256, 0, stream>>>(w_rc, src_rc, r_out_rc, se_rc, E);
    edge_scale<<<1024, 256, 0, stream>>>(w_cr, src_cr, r_out_cr, se_cr, E);

    // ---- layer 1: row -> col ----
    hipMemsetAsync(agg_col, 0, (size_t)NCOL * 64 * sizeof(float), stream);
    scatter_add4<64><<<4096, 256, 0, stream>>>(feat_row, src_rc, dst_rc, se_rc, agg_col, E);
    dense_relu_k<64, false><<<2048, 128, 0, stream>>>(agg_col, r_in_rc, W0_rc, b0_rc, h_col1, NCOL, 0.f);

    // ---- layer 1: col -> row ----
    hipMemsetAsync(agg_row, 0, (size_t)NROW * 64 * sizeof(float), stream);
    scatter_add4<64><<<4096, 256, 0, stream>>>(feat_col, src_cr, dst_cr, se_cr, agg_row, E);
    dense_relu_k<64, false><<<2048, 128, 0, stream>>>(agg_row, r_in_cr, W0_cr, b0_cr, h_row1, NROW, 0.f);

    hipMemsetAsync(out, 0, DH * sizeof(float), stream);

    // ---- layer 2: row -> col (src = h_row1) + fused mean over cols ----
    hipMemsetAsync(agg_col, 0, (size_t)NCOL * DH * sizeof(float), stream);
    scatter_add4<128><<<4096, 256, 0, stream>>>(h_row1, src_rc, dst_rc, se_rc, agg_col, E);
    dense_relu_k<128, true><<<2048, 128, 0, stream>>>(agg_col, r_in_rc, W1_rc, b1_rc, out, NCOL, 1.0f / NCOL);

    // ---- layer 2: col -> row (src = h_col1) + fused mean over rows ----
    hipMemsetAsync(agg_row, 0, (size_t)NROW * DH * sizeof(float), stream);
    scatter_add4<128><<<4096, 256, 0, stream>>>(h_col1, src_cr, dst_cr, se_cr, agg_row, E);
    dense_relu_k<128, true><<<2048, 128, 0, stream>>>(agg_row, r_in_cr, W1_cr, b1_cr, out, NROW, 1.0f / NROW);
}

// Round 3
// 970.816 us; speedup vs baseline: 6.7949x; 6.7949x over previous
//
#include <hip/hip_runtime.h>

constexpr int NROW = 50000;
constexpr int NCOL = 50000;
constexpr int DH   = 128;

// ---- unweighted degree histogram (int), both endpoints of one relation ----
__global__ void hist2(const int* __restrict__ src, const int* __restrict__ dst,
                      int* __restrict__ cnt_src, int* __restrict__ cnt_dst, int E) {
    int stride = gridDim.x * blockDim.x;
    for (int i = blockIdx.x * blockDim.x + threadIdx.x; i < E; i += stride) {
        atomicAdd(&cnt_src[src[i]], 1);
        atomicAdd(&cnt_dst[dst[i]], 1);
    }
}

// norms[i] = 1/sqrt(max(cnt[i],1))
__global__ void make_norms(const int* __restrict__ cnt, float* __restrict__ r, int n) {
    int stride = gridDim.x * blockDim.x;
    for (int i = blockIdx.x * blockDim.x + threadIdx.x; i < n; i += stride)
        r[i] = 1.0f / sqrtf((float)max(cnt[i], 1));
}

// single-block segmented exclusive scan: each thread owns a contiguous segment,
// block-scans the 1024 partial sums (only ~20 __syncthreads total)
__device__ void scan_dev(const int* __restrict__ cnt, int* __restrict__ ptr, int n) {
    constexpr int NT = 1024;
    const int t = threadIdx.x;
    const int seg = (n + NT - 1) / NT;
    const int lo = t * seg, hi = min(lo + seg, n);
    int sum = 0;
    for (int i = lo; i < hi; ++i) sum += cnt[i];
    __shared__ int buf[NT];
    buf[t] = sum;
    __syncthreads();
    for (int off = 1; off < NT; off <<= 1) {
        int v = (t >= off) ? buf[t - off] : 0;
        __syncthreads();
        buf[t] += v;
        __syncthreads();
    }
    int run = buf[t] - sum;                    // exclusive prefix of this segment
    for (int i = lo; i < hi; ++i) { ptr[i] = run; run += cnt[i]; }
    if (t == NT - 1) ptr[n] = buf[NT - 1];
}

__global__ void excl_scan2(const int* cA, int* pA, int nA, const int* cB, int* pB, int nB) {
    if (blockIdx.x == 0) scan_dev(cA, pA, nA);
    else                 scan_dev(cB, pB, nB);
}

// fill CSR: pair[pos] = (src, w*rsqrt(outdeg[src])) grouped by dst
__global__ void csr_fill(const int* __restrict__ src, const int* __restrict__ dst,
                         const float* __restrict__ w, const float* __restrict__ rout,
                         const int* __restrict__ ptr, int* __restrict__ fill,
                         int2* __restrict__ pair, int E) {
    int stride = gridDim.x * blockDim.x;
    for (int i = blockIdx.x * blockDim.x + threadIdx.x; i < E; i += stride) {
        int d = dst[i];
        int pos = ptr[d] + atomicAdd(&fill[d], 1);
        int s = src[i];
        pair[pos] = make_int2(s, __float_as_int(w[i] * rout[s]));
    }
}

// ---- atomic-free aggregate: one wave per dst node, register accumulation ----
template <int D>   // 64 -> 1 float/lane, 128 -> float2/lane
__global__ void gather_agg(const float* __restrict__ h, const int* __restrict__ ptr,
                           const int2* __restrict__ pair, float* __restrict__ agg, int n) {
    const int gwave = (blockIdx.x * blockDim.x + threadIdx.x) >> 6;
    const int lane  = threadIdx.x & 63;
    const int nw    = (gridDim.x * blockDim.x) >> 6;
    for (int node = gwave; node < n; node += nw) {
        const int beg = ptr[node], end = ptr[node + 1];
        if (D == 64) {
            float a0 = 0.f, a1 = 0.f;
            int j = beg;
            for (; j + 1 < end; j += 2) {
                int2 p0 = pair[j], p1 = pair[j + 1];
                a0 = fmaf(h[(size_t)p0.x * 64 + lane], __int_as_float(p0.y), a0);
                a1 = fmaf(h[(size_t)p1.x * 64 + lane], __int_as_float(p1.y), a1);
            }
            if (j < end) {
                int2 p = pair[j];
                a0 = fmaf(h[(size_t)p.x * 64 + lane], __int_as_float(p.y), a0);
            }
            agg[(size_t)node * 64 + lane] = a0 + a1;
        } else {
            float2 a0 = {0.f, 0.f}, a1 = {0.f, 0.f};
            int j = beg;
            for (; j + 1 < end; j += 2) {
                int2 p0 = pair[j], p1 = pair[j + 1];
                float2 h0 = *reinterpret_cast<const float2*>(&h[(size_t)p0.x * 128 + lane * 2]);
                float2 h1 = *reinterpret_cast<const float2*>(&h[(size_t)p1.x * 128 + lane * 2]);
                float w0 = __int_as_float(p0.y), w1 = __int_as_float(p1.y);
                a0.x = fmaf(h0.x, w0, a0.x); a0.y = fmaf(h0.y, w0, a0.y);
                a1.x = fmaf(h1.x, w1, a1.x); a1.y = fmaf(h1.y, w1, a1.y);
            }
            if (j < end) {
                int2 p = pair[j];
                float2 h0 = *reinterpret_cast<const float2*>(&h[(size_t)p.x * 128 + lane * 2]);
                float w0 = __int_as_float(p.y);
                a0.x = fmaf(h0.x, w0, a0.x); a0.y = fmaf(h0.y, w0, a0.y);
            }
            float2 r; r.x = a0.x + a1.x; r.y = a0.y + a1.y;
            *reinterpret_cast<float2*>(&agg[(size_t)node * 128 + lane * 2]) = r;
        }
    }
}

// ---- dense epilogue: relu(rin[node]*(agg[node,:]@W)+b), 8 nodes/iter register-blocked ----
template <int K, bool MEANSUM>
__global__ void dense_relu_k(const float* __restrict__ agg, const float* __restrict__ rin,
                             const float* __restrict__ W, const float* __restrict__ b,
                             float* __restrict__ out, int n, float invn) {
    constexpr int NB = 8;
    constexpr int LOGK = (K == 64) ? 6 : 7;
    __shared__ float a[NB][K];
    const int t = threadIdx.x;                   // one output column each
    const float bias = b[t];
    float acc = 0.f;
    for (int base = blockIdx.x * NB; base < n; base += gridDim.x * NB) {
#pragma unroll
        for (int j = 0; j < NB * K / 128; ++j) {
            int idx = t + j * 128;
            int r = idx >> LOGK, c = idx & (K - 1);
            int node = base + r;
            a[r][c] = (node < n) ? agg[(size_t)node * K + c] : 0.f;
        }
        __syncthreads();
        float s[NB];
#pragma unroll
        for (int r = 0; r < NB; ++r) s[r] = 0.f;
#pragma unroll 4
        for (int k = 0; k < K; ++k) {
            const float wk = W[k * DH + t];
#pragma unroll
            for (int r = 0; r < NB; ++r) s[r] = fmaf(a[r][k], wk, s[r]);
        }
#pragma unroll
        for (int r = 0; r < NB; ++r) {
            const int node = base + r;
            if (node < n) {
                const float v = fmaxf(fmaf(rin[node], s[r], bias), 0.f);
                if (MEANSUM) acc += v;
                else out[(size_t)node * DH + t] = v;
            }
        }
        __syncthreads();
    }
    if (MEANSUM) atomicAdd(&out[t], acc * invn);
}

extern "C" void kernel_launch(void* const* d_in, const int* in_sizes, int n_in,
                              void* d_out, int out_size, void* d_ws, size_t ws_size,
                              hipStream_t stream) {
    const float* feat_row = (const float*)d_in[0];
    const float* feat_col = (const float*)d_in[1];
    const int*   src_rc   = (const int*)d_in[2];
    const int*   dst_rc   = (const int*)d_in[3];
    const float* w_rc     = (const float*)d_in[4];
    const int*   src_cr   = (const int*)d_in[5];
    const int*   dst_cr   = (const int*)d_in[6];
    const float* w_cr     = (const float*)d_in[7];
    const float* W0_rc    = (const float*)d_in[8];
    const float* b0_rc    = (const float*)d_in[9];
    const float* W0_cr    = (const float*)d_in[10];
    const float* b0_cr    = (const float*)d_in[11];
    const float* W1_rc    = (const float*)d_in[12];
    const float* b1_rc    = (const float*)d_in[13];
    const float* W1_cr    = (const float*)d_in[14];
    const float* b1_cr    = (const float*)d_in[15];
    const int E = in_sizes[2];
    float* out = (float*)d_out;

    // workspace layout (~124 MB)
    int*   cnt     = (int*)d_ws;                    // 200000: [out_rc|in_rc|out_cr|in_cr]
    int*   fill_rc = cnt + 200000;                  // 50000
    int*   fill_cr = fill_rc + 50000;               // 50000
    float* norms   = (float*)(fill_cr + 50000);     // 200000, same order as cnt
    int*   ptr_rc  = (int*)(norms + 200000);        // 50004 (uses 50001)
    int*   ptr_cr  = ptr_rc + 50004;                // 50004
    int2*  pair_rc = (int2*)(ptr_cr + 50004);       // E
    int2*  pair_cr = pair_rc + E;                   // E
    float* agg_col = (float*)(pair_cr + E);         // NCOL*128
    float* agg_row = agg_col + (size_t)NCOL * DH;   // NROW*128
    float* h_col1  = agg_row + (size_t)NROW * DH;
    float* h_row1  = h_col1  + (size_t)NCOL * DH;

    int*   c_out_rc = cnt;
    int*   c_in_rc  = cnt + NROW;
    int*   c_out_cr = cnt + NROW + NCOL;
    int*   c_in_cr  = cnt + NROW + 2 * NCOL;
    float* r_out_rc = norms;
    float* r_in_rc  = norms + NROW;
    float* r_out_cr = norms + NROW + NCOL;
    float* r_in_cr  = norms + NROW + 2 * NCOL;

    // ---- CSR build (shared by both layers) ----
    hipMemsetAsync(cnt, 0, 300000 * sizeof(int), stream);   // cnt + fill counters
    hist2<<<1024, 256, 0, stream>>>(src_rc, dst_rc, c_out_rc, c_in_rc, E);
    hist2<<<1024, 256, 0, stream>>>(src_cr, dst_cr, c_out_cr, c_in_cr, E);
    make_norms<<<200, 1024, 0, stream>>>(cnt, norms, 200000);
    excl_scan2<<<2, 1024, 0, stream>>>(c_in_rc, ptr_rc, NCOL, c_in_cr, ptr_cr, NROW);
    csr_fill<<<1024, 256, 0, stream>>>(src_rc, dst_rc, w_rc, r_out_rc, ptr_rc, fill_rc, pair_rc, E);
    csr_fill<<<1024, 256, 0, stream>>>(src_cr, dst_cr, w_cr, r_out_cr, ptr_cr, fill_cr, pair_cr, E);

    // ---- layer 1 ----
    gather_agg<64><<<2048, 256, 0, stream>>>(feat_row, ptr_rc, pair_rc, agg_col, NCOL);
    dense_relu_k<64, false><<<2048, 128, 0, stream>>>(agg_col, r_in_rc, W0_rc, b0_rc, h_col1, NCOL, 0.f);
    gather_agg<64><<<2048, 256, 0, stream>>>(feat_col, ptr_cr, pair_cr, agg_row, NROW);
    dense_relu_k<64, false><<<2048, 128, 0, stream>>>(agg_row, r_in_cr, W0_cr, b0_cr, h_row1, NROW, 0.f);

    hipMemsetAsync(out, 0, DH * sizeof(float), stream);

    // ---- layer 2 + fused mean pooling ----
    gather_agg<128><<<2048, 256, 0, stream>>>(h_row1, ptr_rc, pair_rc, agg_col, NCOL);
    dense_relu_k<128, true><<<2048, 128, 0, stream>>>(agg_col, r_in_rc, W1_rc, b1_rc, out, NCOL, 1.0f / NCOL);
    gather_agg<128><<<2048, 256, 0, stream>>>(h_col1, ptr_cr, pair_cr, agg_row, NROW);
    dense_relu_k<128, true><<<2048, 128, 0, stream>>>(agg_row, r_in_cr, W1_cr, b1_cr, out, NROW, 1.0f / NROW);
}

// Round 4
// 833.789 us; speedup vs baseline: 7.9116x; 1.1643x over previous
//
#include <hip/hip_runtime.h>

constexpr int NROW = 50000;
constexpr int NCOL = 50000;
constexpr int DH   = 128;

__device__ __forceinline__ float bf_lo(unsigned u) { return __uint_as_float(u << 16); }
__device__ __forceinline__ float bf_hi(unsigned u) { return __uint_as_float(u & 0xffff0000u); }
__device__ __forceinline__ unsigned short f2bf(float f) {   // RNE
    unsigned u = __float_as_uint(f);
    return (unsigned short)((u + 0x7fffu + ((u >> 16) & 1u)) >> 16);
}

// ---- degree histograms for both relations in one pass ----
__global__ void hist4(const int* __restrict__ sA, const int* __restrict__ dA,
                      const int* __restrict__ sB, const int* __restrict__ dB,
                      int* __restrict__ cA0, int* __restrict__ cA1,
                      int* __restrict__ cB0, int* __restrict__ cB1, int E) {
    int stride = gridDim.x * blockDim.x;
    for (int i = blockIdx.x * blockDim.x + threadIdx.x; i < E; i += stride) {
        atomicAdd(&cA0[sA[i]], 1);
        atomicAdd(&cA1[dA[i]], 1);
        atomicAdd(&cB0[sB[i]], 1);
        atomicAdd(&cB1[dB[i]], 1);
    }
}

// norms[i] = 1/sqrt(max(cnt[i],1))
__global__ void make_norms(const int* __restrict__ cnt, float* __restrict__ r, int n) {
    int stride = gridDim.x * blockDim.x;
    for (int i = blockIdx.x * blockDim.x + threadIdx.x; i < n; i += stride)
        r[i] = 1.0f / sqrtf((float)max(cnt[i], 1));
}

// single-block segmented exclusive scan (1024 threads)
__device__ void scan_dev(const int* __restrict__ cnt, int* __restrict__ ptr, int n) {
    constexpr int NT = 1024;
    const int t = threadIdx.x;
    const int seg = (n + NT - 1) / NT;
    const int lo = t * seg, hi = min(lo + seg, n);
    int sum = 0;
    for (int i = lo; i < hi; ++i) sum += cnt[i];
    __shared__ int buf[NT];
    buf[t] = sum;
    __syncthreads();
    for (int off = 1; off < NT; off <<= 1) {
        int v = (t >= off) ? buf[t - off] : 0;
        __syncthreads();
        buf[t] += v;
        __syncthreads();
    }
    int run = buf[t] - sum;
    for (int i = lo; i < hi; ++i) { ptr[i] = run; run += cnt[i]; }
    if (t == NT - 1) ptr[n] = buf[NT - 1];
}

__global__ void excl_scan2(const int* cA, int* pA, int nA, const int* cB, int* pB, int nB) {
    if (blockIdx.x == 0) scan_dev(cA, pA, nA);
    else                 scan_dev(cB, pB, nB);
}

// fill CSR for both relations (grid split): pair[pos] = (src, w*rsqrt(outdeg[src]))
__global__ void csr_fill2(const int* __restrict__ srcA, const int* __restrict__ dstA,
                          const float* __restrict__ wA, const float* __restrict__ routA,
                          const int* __restrict__ ptrA, int* __restrict__ fillA, int2* __restrict__ pairA,
                          const int* __restrict__ srcB, const int* __restrict__ dstB,
                          const float* __restrict__ wB, const float* __restrict__ routB,
                          const int* __restrict__ ptrB, int* __restrict__ fillB, int2* __restrict__ pairB,
                          int E) {
    const int nb = gridDim.x >> 1;
    const bool second = blockIdx.x >= nb;
    const int bid = second ? blockIdx.x - nb : blockIdx.x;
    const int* __restrict__ src  = second ? srcB  : srcA;
    const int* __restrict__ dst  = second ? dstB  : dstA;
    const float* __restrict__ w  = second ? wB    : wA;
    const float* __restrict__ ro = second ? routB : routA;
    const int* __restrict__ ptr  = second ? ptrB  : ptrA;
    int* __restrict__ fill       = second ? fillB : fillA;
    int2* __restrict__ pair      = second ? pairB : pairA;
    const int stride = nb * blockDim.x;
    for (int i = bid * blockDim.x + threadIdx.x; i < E; i += stride) {
        int d = dst[i];
        int pos = ptr[d] + atomicAdd(&fill[d], 1);
        int s = src[i];
        pair[pos] = make_int2(s, __float_as_int(w[i] * ro[s]));
    }
}

// ---- fp32 -> bf16 feature tables (both in one launch) ----
__global__ void feats_to_bf16(const float4* __restrict__ fr, const float4* __restrict__ fc,
                              ushort4* __restrict__ br, ushort4* __restrict__ bc, int nq) {
    int stride = gridDim.x * blockDim.x;
    for (int i = blockIdx.x * blockDim.x + threadIdx.x; i < 2 * nq; i += stride) {
        bool second = i >= nq;
        int k = second ? i - nq : i;
        float4 v = second ? fc[k] : fr[k];
        ushort4 o;
        o.x = f2bf(v.x); o.y = f2bf(v.y); o.z = f2bf(v.z); o.w = f2bf(v.w);
        if (second) bc[k] = o; else br[k] = o;
    }
}

// ---- D=64 gather: full wave per node, 2 edges/iter (half-wave each), unroll 2 ----
__global__ void gather64_bf16(const unsigned short* __restrict__ h, const int* __restrict__ ptr,
                              const int2* __restrict__ pair, float* __restrict__ agg, int n) {
    const int gw   = (blockIdx.x * blockDim.x + threadIdx.x) >> 6;
    const int nw   = (gridDim.x * blockDim.x) >> 6;
    const int lane = threadIdx.x & 63;
    const int half = lane >> 5;
    const int c    = (lane & 31) << 1;          // column pair 0..62
    for (int node = gw; node < n; node += nw) {
        const int beg = ptr[node], end = ptr[node + 1];
        float ax0 = 0.f, ay0 = 0.f, ax1 = 0.f, ay1 = 0.f;
        int j = beg + half;
        for (; j + 2 < end; j += 4) {
            int2 p0 = pair[j], p1 = pair[j + 2];
            unsigned h0 = *reinterpret_cast<const unsigned*>(&h[(size_t)p0.x * 64 + c]);
            unsigned h1 = *reinterpret_cast<const unsigned*>(&h[(size_t)p1.x * 64 + c]);
            float w0 = __int_as_float(p0.y), w1 = __int_as_float(p1.y);
            ax0 = fmaf(bf_lo(h0), w0, ax0); ay0 = fmaf(bf_hi(h0), w0, ay0);
            ax1 = fmaf(bf_lo(h1), w1, ax1); ay1 = fmaf(bf_hi(h1), w1, ay1);
        }
        for (; j < end; j += 2) {
            int2 p = pair[j];
            unsigned hv = *reinterpret_cast<const unsigned*>(&h[(size_t)p.x * 64 + c]);
            float w = __int_as_float(p.y);
            ax0 = fmaf(bf_lo(hv), w, ax0); ay0 = fmaf(bf_hi(hv), w, ay0);
        }
        float ax = ax0 + ax1, ay = ay0 + ay1;
        ax += __shfl_xor(ax, 32);
        ay += __shfl_xor(ay, 32);
        if (half == 0) {
            float2 r; r.x = ax; r.y = ay;
            *reinterpret_cast<float2*>(&agg[(size_t)node * 64 + c]) = r;
        }
    }
}

// ---- D=128 gather: full wave per node, lane holds 2 bf16 cols, 2 edges in flight ----
__global__ void gather128_bf16(const unsigned short* __restrict__ h, const int* __restrict__ ptr,
                               const int2* __restrict__ pair, float* __restrict__ agg, int n) {
    const int gw   = (blockIdx.x * blockDim.x + threadIdx.x) >> 6;
    const int nw   = (gridDim.x * blockDim.x) >> 6;
    const int lane = threadIdx.x & 63;
    const int c    = lane << 1;                 // column pair 0..126
    for (int node = gw; node < n; node += nw) {
        const int beg = ptr[node], end = ptr[node + 1];
        float ax0 = 0.f, ay0 = 0.f, ax1 = 0.f, ay1 = 0.f;
        int j = beg;
        for (; j + 1 < end; j += 2) {
            int2 p0 = pair[j], p1 = pair[j + 1];
            unsigned h0 = *reinterpret_cast<const unsigned*>(&h[(size_t)p0.x * 128 + c]);
            unsigned h1 = *reinterpret_cast<const unsigned*>(&h[(size_t)p1.x * 128 + c]);
            float w0 = __int_as_float(p0.y), w1 = __int_as_float(p1.y);
            ax0 = fmaf(bf_lo(h0), w0, ax0); ay0 = fmaf(bf_hi(h0), w0, ay0);
            ax1 = fmaf(bf_lo(h1), w1, ax1); ay1 = fmaf(bf_hi(h1), w1, ay1);
        }
        if (j < end) {
            int2 p = pair[j];
            unsigned hv = *reinterpret_cast<const unsigned*>(&h[(size_t)p.x * 128 + c]);
            float w = __int_as_float(p.y);
            ax0 = fmaf(bf_lo(hv), w, ax0); ay0 = fmaf(bf_hi(hv), w, ay0);
        }
        float2 r; r.x = ax0 + ax1; r.y = ay0 + ay1;
        *reinterpret_cast<float2*>(&agg[(size_t)node * 128 + c]) = r;
    }
}

// ---- dense epilogue: relu(rin*(agg@W)+b); 8 nodes/iter; optional bf16 out / mean-pool ----
template <int K, bool MEANSUM, bool OUTBF16>
__global__ void dense_relu_k(const float* __restrict__ agg, const float* __restrict__ rin,
                             const float* __restrict__ W, const float* __restrict__ b,
                             void* __restrict__ outv, int n, float invn) {
    constexpr int NB = 8;
    constexpr int LOGK = (K == 64) ? 6 : 7;
    __shared__ float a[NB][K];
    const int t = threadIdx.x;                   // one output column each
    const float bias = b[t];
    float acc = 0.f;
    for (int base = blockIdx.x * NB; base < n; base += gridDim.x * NB) {
#pragma unroll
        for (int j = 0; j < NB * K / 128; ++j) {
            int idx = t + j * 128;
            int r = idx >> LOGK, c = idx & (K - 1);
            int node = base + r;
            a[r][c] = (node < n) ? agg[(size_t)node * K + c] : 0.f;
        }
        __syncthreads();
        float s[NB];
#pragma unroll
        for (int r = 0; r < NB; ++r) s[r] = 0.f;
#pragma unroll 4
        for (int k = 0; k < K; ++k) {
            const float wk = W[k * DH + t];
#pragma unroll
            for (int r = 0; r < NB; ++r) s[r] = fmaf(a[r][k], wk, s[r]);
        }
#pragma unroll
        for (int r = 0; r < NB; ++r) {
            const int node = base + r;
            if (node < n) {
                const float v = fmaxf(fmaf(rin[node], s[r], bias), 0.f);
                if (MEANSUM) acc += v;
                else if (OUTBF16) ((unsigned short*)outv)[(size_t)node * DH + t] = f2bf(v);
                else ((float*)outv)[(size_t)node * DH + t] = v;
            }
        }
        __syncthreads();
    }
    if (MEANSUM) atomicAdd(&((float*)outv)[t], acc * invn);
}

extern "C" void kernel_launch(void* const* d_in, const int* in_sizes, int n_in,
                              void* d_out, int out_size, void* d_ws, size_t ws_size,
                              hipStream_t stream) {
    const float* feat_row = (const float*)d_in[0];
    const float* feat_col = (const float*)d_in[1];
    const int*   src_rc   = (const int*)d_in[2];
    const int*   dst_rc   = (const int*)d_in[3];
    const float* w_rc     = (const float*)d_in[4];
    const int*   src_cr   = (const int*)d_in[5];
    const int*   dst_cr   = (const int*)d_in[6];
    const float* w_cr     = (const float*)d_in[7];
    const float* W0_rc    = (const float*)d_in[8];
    const float* b0_rc    = (const float*)d_in[9];
    const float* W0_cr    = (const float*)d_in[10];
    const float* b0_cr    = (const float*)d_in[11];
    const float* W1_rc    = (const float*)d_in[12];
    const float* b1_rc    = (const float*)d_in[13];
    const float* W1_cr    = (const float*)d_in[14];
    const float* b1_cr    = (const float*)d_in[15];
    const int E = in_sizes[2];
    float* out = (float*)d_out;

    // workspace layout (~111 MB)
    int*   cnt     = (int*)d_ws;                        // 200000 [out_rc|in_rc|out_cr|in_cr]
    int*   fill    = cnt + 200000;                      // 100000 [fill_rc|fill_cr]
    float* norms   = (float*)(fill + 100000);           // 200000 same order as cnt
    int*   ptr_rc  = (int*)(norms + 200000);            // 50004
    int*   ptr_cr  = ptr_rc + 50004;                    // 50004
    int2*  pair_rc = (int2*)(ptr_cr + 50004);           // E
    int2*  pair_cr = pair_rc + E;                       // E
    float* agg_col = (float*)(pair_cr + E);             // NCOL*128
    float* agg_row = agg_col + (size_t)NCOL * DH;       // NROW*128
    unsigned short* bf_row = (unsigned short*)(agg_row + (size_t)NROW * DH); // NROW*64
    unsigned short* bf_col = bf_row + (size_t)NROW * 64;                     // NCOL*64
    unsigned short* h_col1 = bf_col + (size_t)NCOL * 64;                     // NCOL*128
    unsigned short* h_row1 = h_col1 + (size_t)NCOL * DH;                     // NROW*128

    int*   c_out_rc = cnt;
    int*   c_in_rc  = cnt + NROW;
    int*   c_out_cr = cnt + NROW + NCOL;
    int*   c_in_cr  = cnt + NROW + 2 * NCOL;
    float* r_out_rc = norms;
    float* r_in_rc  = norms + NROW;
    float* r_out_cr = norms + NROW + NCOL;
    float* r_in_cr  = norms + NROW + 2 * NCOL;
    int*   fill_rc  = fill;
    int*   fill_cr  = fill + NCOL;

    // ---- CSR build (shared by both layers) + bf16 feature tables ----
    hipMemsetAsync(cnt, 0, 300000 * sizeof(int), stream);
    feats_to_bf16<<<2048, 256, 0, stream>>>((const float4*)feat_row, (const float4*)feat_col,
                                            (ushort4*)bf_row, (ushort4*)bf_col, NROW * 64 / 4);
    hist4<<<1024, 256, 0, stream>>>(src_rc, dst_rc, src_cr, dst_cr,
                                    c_out_rc, c_in_rc, c_out_cr, c_in_cr, E);
    make_norms<<<200, 1024, 0, stream>>>(cnt, norms, 200000);
    excl_scan2<<<2, 1024, 0, stream>>>(c_in_rc, ptr_rc, NCOL, c_in_cr, ptr_cr, NROW);
    csr_fill2<<<2048, 256, 0, stream>>>(src_rc, dst_rc, w_rc, r_out_rc, ptr_rc, fill_rc, pair_rc,
                                        src_cr, dst_cr, w_cr, r_out_cr, ptr_cr, fill_cr, pair_cr, E);

    // ---- layer 1 ----
    gather64_bf16<<<2048, 256, 0, stream>>>(bf_row, ptr_rc, pair_rc, agg_col, NCOL);
    dense_relu_k<64, false, true><<<2048, 128, 0, stream>>>(agg_col, r_in_rc, W0_rc, b0_rc, h_col1, NCOL, 0.f);
    gather64_bf16<<<2048, 256, 0, stream>>>(bf_col, ptr_cr, pair_cr, agg_row, NROW);
    dense_relu_k<64, false, true><<<2048, 128, 0, stream>>>(agg_row, r_in_cr, W0_cr, b0_cr, h_row1, NROW, 0.f);

    hipMemsetAsync(out, 0, DH * sizeof(float), stream);

    // ---- layer 2 + fused mean pooling ----
    gather128_bf16<<<2048, 256, 0, stream>>>(h_row1, ptr_rc, pair_rc, agg_col, NCOL);
    dense_relu_k<128, true, false><<<1024, 128, 0, stream>>>(agg_col, r_in_rc, W1_rc, b1_rc, out, NCOL, 1.0f / NCOL);
    gather128_bf16<<<2048, 256, 0, stream>>>(h_col1, ptr_cr, pair_cr, agg_row, NROW);
    dense_relu_k<128, true, false><<<1024, 128, 0, stream>>>(agg_row, r_in_cr, W1_cr, b1_cr, out, NROW, 1.0f / NROW);
}

// Round 5
// 830.685 us; speedup vs baseline: 7.9412x; 1.0037x over previous
//
#include <hip/hip_runtime.h>

constexpr int NROW = 50000;
constexpr int NCOL = 50000;
constexpr int DH   = 128;
constexpr int NTAB = 200000;        // [out_rc(NROW) | in_rc(NCOL) | out_cr(NCOL) | in_cr(NROW)]
constexpr int NXCD = 8;

__device__ __forceinline__ float bf_lo(unsigned u) { return __uint_as_float(u << 16); }
__device__ __forceinline__ float bf_hi(unsigned u) { return __uint_as_float(u & 0xffff0000u); }
__device__ __forceinline__ unsigned short f2bf(float f) {   // RNE
    unsigned u = __float_as_uint(f);
    return (unsigned short)((u + 0x7fffu + ((u >> 16) & 1u)) >> 16);
}

// physical XCD id of the executing CU (gfx940+: hwreg 20 = HW_REG_XCC_ID)
__device__ __forceinline__ int xcc_id() {
    return __builtin_amdgcn_s_getreg((31u << 11) | (0u << 6) | 20u) & (NXCD - 1);
}

// ---- degree histograms, XCD-private copies + workgroup-scope (L2-local) atomics ----
__global__ void hist_local(const int* __restrict__ sA, const int* __restrict__ dA,
                           const int* __restrict__ sB, const int* __restrict__ dB,
                           int* __restrict__ h8, int E) {
    int* __restrict__ h = h8 + (size_t)xcc_id() * NTAB;
    int stride = gridDim.x * blockDim.x;
    for (int i = blockIdx.x * blockDim.x + threadIdx.x; i < E; i += stride) {
        __hip_atomic_fetch_add(&h[sA[i]],                 1, __ATOMIC_RELAXED, __HIP_MEMORY_SCOPE_WORKGROUP);
        __hip_atomic_fetch_add(&h[NROW + dA[i]],          1, __ATOMIC_RELAXED, __HIP_MEMORY_SCOPE_WORKGROUP);
        __hip_atomic_fetch_add(&h[NROW + NCOL + sB[i]],   1, __ATOMIC_RELAXED, __HIP_MEMORY_SCOPE_WORKGROUP);
        __hip_atomic_fetch_add(&h[2 * NCOL + NROW + dB[i]], 1, __ATOMIC_RELAXED, __HIP_MEMORY_SCOPE_WORKGROUP);
    }
}

// ---- reduce 8 copies -> cnt + norms ----
__global__ void reduce_norms(const int* __restrict__ h8, int* __restrict__ cnt,
                             float* __restrict__ norms) {
    int stride = gridDim.x * blockDim.x;
    for (int i = blockIdx.x * blockDim.x + threadIdx.x; i < NTAB; i += stride) {
        int s = 0;
#pragma unroll
        for (int x = 0; x < NXCD; ++x) s += h8[(size_t)x * NTAB + i];
        cnt[i] = s;
        norms[i] = 1.0f / sqrtf((float)max(s, 1));
    }
}

// single-block segmented exclusive scan (1024 threads)
__device__ void scan_dev(const int* __restrict__ cnt, int* __restrict__ ptr, int n) {
    constexpr int NT = 1024;
    const int t = threadIdx.x;
    const int seg = (n + NT - 1) / NT;
    const int lo = t * seg, hi = min(lo + seg, n);
    int sum = 0;
    for (int i = lo; i < hi; ++i) sum += cnt[i];
    __shared__ int buf[NT];
    buf[t] = sum;
    __syncthreads();
    for (int off = 1; off < NT; off <<= 1) {
        int v = (t >= off) ? buf[t - off] : 0;
        __syncthreads();
        buf[t] += v;
        __syncthreads();
    }
    int run = buf[t] - sum;
    for (int i = lo; i < hi; ++i) { ptr[i] = run; run += cnt[i]; }
    if (t == NT - 1) ptr[n] = buf[NT - 1];
}

__global__ void excl_scan2(const int* cA, int* pA, int nA, const int* cB, int* pB, int nB) {
    if (blockIdx.x == 0) scan_dev(cA, pA, nA);
    else                 scan_dev(cB, pB, nB);
}

// fill CSR for both relations (grid split): pair[pos] = (src, w*rsqrt(outdeg[src]))
__global__ void csr_fill2(const int* __restrict__ srcA, const int* __restrict__ dstA,
                          const float* __restrict__ wA, const float* __restrict__ routA,
                          const int* __restrict__ ptrA, int* __restrict__ fillA, int2* __restrict__ pairA,
                          const int* __restrict__ srcB, const int* __restrict__ dstB,
                          const float* __restrict__ wB, const float* __restrict__ routB,
                          const int* __restrict__ ptrB, int* __restrict__ fillB, int2* __restrict__ pairB,
                          int E) {
    const int nb = gridDim.x >> 1;
    const bool second = blockIdx.x >= nb;
    const int bid = second ? blockIdx.x - nb : blockIdx.x;
    const int* __restrict__ src  = second ? srcB  : srcA;
    const int* __restrict__ dst  = second ? dstB  : dstA;
    const float* __restrict__ w  = second ? wB    : wA;
    const float* __restrict__ ro = second ? routB : routA;
    const int* __restrict__ ptr  = second ? ptrB  : ptrA;
    int* __restrict__ fill       = second ? fillB : fillA;
    int2* __restrict__ pair      = second ? pairB : pairA;
    const int stride = nb * blockDim.x;
    for (int i = bid * blockDim.x + threadIdx.x; i < E; i += stride) {
        int d = dst[i];
        int pos = ptr[d] + atomicAdd(&fill[d], 1);
        int s = src[i];
        pair[pos] = make_int2(s, __float_as_int(w[i] * ro[s]));
    }
}

// ---- fp32 -> bf16 feature tables (both in one launch) ----
__global__ void feats_to_bf16(const float4* __restrict__ fr, const float4* __restrict__ fc,
                              ushort4* __restrict__ br, ushort4* __restrict__ bc, int nq) {
    int stride = gridDim.x * blockDim.x;
    for (int i = blockIdx.x * blockDim.x + threadIdx.x; i < 2 * nq; i += stride) {
        bool second = i >= nq;
        int k = second ? i - nq : i;
        float4 v = second ? fc[k] : fr[k];
        ushort4 o;
        o.x = f2bf(v.x); o.y = f2bf(v.y); o.z = f2bf(v.z); o.w = f2bf(v.w);
        if (second) bc[k] = o; else br[k] = o;
    }
}

// ---- D=64 gather: full wave per node, 2 edges/iter (half-wave each), unroll 2 ----
__global__ void gather64_bf16(const unsigned short* __restrict__ h, const int* __restrict__ ptr,
                              const int2* __restrict__ pair, float* __restrict__ agg, int n) {
    const int gw   = (blockIdx.x * blockDim.x + threadIdx.x) >> 6;
    const int nw   = (gridDim.x * blockDim.x) >> 6;
    const int lane = threadIdx.x & 63;
    const int half = lane >> 5;
    const int c    = (lane & 31) << 1;          // column pair 0..62
    for (int node = gw; node < n; node += nw) {
        const int beg = ptr[node], end = ptr[node + 1];
        float ax0 = 0.f, ay0 = 0.f, ax1 = 0.f, ay1 = 0.f;
        int j = beg + half;
        for (; j + 2 < end; j += 4) {
            int2 p0 = pair[j], p1 = pair[j + 2];
            unsigned h0 = *reinterpret_cast<const unsigned*>(&h[(size_t)p0.x * 64 + c]);
            unsigned h1 = *reinterpret_cast<const unsigned*>(&h[(size_t)p1.x * 64 + c]);
            float w0 = __int_as_float(p0.y), w1 = __int_as_float(p1.y);
            ax0 = fmaf(bf_lo(h0), w0, ax0); ay0 = fmaf(bf_hi(h0), w0, ay0);
            ax1 = fmaf(bf_lo(h1), w1, ax1); ay1 = fmaf(bf_hi(h1), w1, ay1);
        }
        for (; j < end; j += 2) {
            int2 p = pair[j];
            unsigned hv = *reinterpret_cast<const unsigned*>(&h[(size_t)p.x * 64 + c]);
            float w = __int_as_float(p.y);
            ax0 = fmaf(bf_lo(hv), w, ax0); ay0 = fmaf(bf_hi(hv), w, ay0);
        }
        float ax = ax0 + ax1, ay = ay0 + ay1;
        ax += __shfl_xor(ax, 32);
        ay += __shfl_xor(ay, 32);
        if (half == 0) {
            float2 r; r.x = ax; r.y = ay;
            *reinterpret_cast<float2*>(&agg[(size_t)node * 64 + c]) = r;
        }
    }
}

// ---- D=128 gather: full wave per node, lane holds 2 bf16 cols, 2 edges in flight ----
__global__ void gather128_bf16(const unsigned short* __restrict__ h, const int* __restrict__ ptr,
                               const int2* __restrict__ pair, float* __restrict__ agg, int n) {
    const int gw   = (blockIdx.x * blockDim.x + threadIdx.x) >> 6;
    const int nw   = (gridDim.x * blockDim.x) >> 6;
    const int lane = threadIdx.x & 63;
    const int c    = lane << 1;                 // column pair 0..126
    for (int node = gw; node < n; node += nw) {
        const int beg = ptr[node], end = ptr[node + 1];
        float ax0 = 0.f, ay0 = 0.f, ax1 = 0.f, ay1 = 0.f;
        int j = beg;
        for (; j + 1 < end; j += 2) {
            int2 p0 = pair[j], p1 = pair[j + 1];
            unsigned h0 = *reinterpret_cast<const unsigned*>(&h[(size_t)p0.x * 128 + c]);
            unsigned h1 = *reinterpret_cast<const unsigned*>(&h[(size_t)p1.x * 128 + c]);
            float w0 = __int_as_float(p0.y), w1 = __int_as_float(p1.y);
            ax0 = fmaf(bf_lo(h0), w0, ax0); ay0 = fmaf(bf_hi(h0), w0, ay0);
            ax1 = fmaf(bf_lo(h1), w1, ax1); ay1 = fmaf(bf_hi(h1), w1, ay1);
        }
        if (j < end) {
            int2 p = pair[j];
            unsigned hv = *reinterpret_cast<const unsigned*>(&h[(size_t)p.x * 128 + c]);
            float w = __int_as_float(p.y);
            ax0 = fmaf(bf_lo(hv), w, ax0); ay0 = fmaf(bf_hi(hv), w, ay0);
        }
        float2 r; r.x = ax0 + ax1; r.y = ay0 + ay1;
        *reinterpret_cast<float2*>(&agg[(size_t)node * 128 + c]) = r;
    }
}

// ---- dense epilogue: relu(rin*(agg@W)+b); 8 nodes/iter; optional bf16 out / mean-pool ----
template <int K, bool MEANSUM, bool OUTBF16>
__global__ void dense_relu_k(const float* __restrict__ agg, const float* __restrict__ rin,
                             const float* __restrict__ W, const float* __restrict__ b,
                             void* __restrict__ outv, int n, float invn) {
    constexpr int NB = 8;
    constexpr int LOGK = (K == 64) ? 6 : 7;
    __shared__ float a[NB][K];
    const int t = threadIdx.x;                   // one output column each
    const float bias = b[t];
    float acc = 0.f;
    for (int base = blockIdx.x * NB; base < n; base += gridDim.x * NB) {
#pragma unroll
        for (int j = 0; j < NB * K / 128; ++j) {
            int idx = t + j * 128;
            int r = idx >> LOGK, c = idx & (K - 1);
            int node = base + r;
            a[r][c] = (node < n) ? agg[(size_t)node * K + c] : 0.f;
        }
        __syncthreads();
        float s[NB];
#pragma unroll
        for (int r = 0; r < NB; ++r) s[r] = 0.f;
#pragma unroll 4
        for (int k = 0; k < K; ++k) {
            const float wk = W[k * DH + t];
#pragma unroll
            for (int r = 0; r < NB; ++r) s[r] = fmaf(a[r][k], wk, s[r]);
        }
#pragma unroll
        for (int r = 0; r < NB; ++r) {
            const int node = base + r;
            if (node < n) {
                const float v = fmaxf(fmaf(rin[node], s[r], bias), 0.f);
                if (MEANSUM) acc += v;
                else if (OUTBF16) ((unsigned short*)outv)[(size_t)node * DH + t] = f2bf(v);
                else ((float*)outv)[(size_t)node * DH + t] = v;
            }
        }
        __syncthreads();
    }
    if (MEANSUM) atomicAdd(&((float*)outv)[t], acc * invn);
}

extern "C" void kernel_launch(void* const* d_in, const int* in_sizes, int n_in,
                              void* d_out, int out_size, void* d_ws, size_t ws_size,
                              hipStream_t stream) {
    const float* feat_row = (const float*)d_in[0];
    const float* feat_col = (const float*)d_in[1];
    const int*   src_rc   = (const int*)d_in[2];
    const int*   dst_rc   = (const int*)d_in[3];
    const float* w_rc     = (const float*)d_in[4];
    const int*   src_cr   = (const int*)d_in[5];
    const int*   dst_cr   = (const int*)d_in[6];
    const float* w_cr     = (const float*)d_in[7];
    const float* W0_rc    = (const float*)d_in[8];
    const float* b0_rc    = (const float*)d_in[9];
    const float* W0_cr    = (const float*)d_in[10];
    const float* b0_cr    = (const float*)d_in[11];
    const float* W1_rc    = (const float*)d_in[12];
    const float* b1_rc    = (const float*)d_in[13];
    const float* W1_cr    = (const float*)d_in[14];
    const float* b1_cr    = (const float*)d_in[15];
    const int E = in_sizes[2];
    float* out = (float*)d_out;

    // workspace layout (~111 MB); hist8 (6.4 MB) aliases the not-yet-live agg_col
    int*   cnt     = (int*)d_ws;                        // 200000
    int*   fill    = cnt + 200000;                      // 100000 [fill_rc|fill_cr]
    float* norms   = (float*)(fill + 100000);           // 200000 same order as cnt
    int*   ptr_rc  = (int*)(norms + 200000);            // 50004
    int*   ptr_cr  = ptr_rc + 50004;                    // 50004
    int2*  pair_rc = (int2*)(ptr_cr + 50004);           // E
    int2*  pair_cr = pair_rc + E;                       // E
    float* agg_col = (float*)(pair_cr + E);             // NCOL*128
    float* agg_row = agg_col + (size_t)NCOL * DH;       // NROW*128
    unsigned short* bf_row = (unsigned short*)(agg_row + (size_t)NROW * DH); // NROW*64
    unsigned short* bf_col = bf_row + (size_t)NROW * 64;                     // NCOL*64
    unsigned short* h_col1 = bf_col + (size_t)NCOL * 64;                     // NCOL*128
    unsigned short* h_row1 = h_col1 + (size_t)NCOL * DH;                     // NROW*128
    int*   hist8   = (int*)agg_col;                     // NXCD*NTAB ints, dead before gathers

    float* r_out_rc = norms;
    float* r_in_rc  = norms + NROW;
    float* r_out_cr = norms + NROW + NCOL;
    int*   c_in_rc  = cnt + NROW;
    int*   c_in_cr  = cnt + NROW + 2 * NCOL;
    float* r_in_rc_ = norms + NROW;
    float* r_in_cr  = norms + NROW + 2 * NCOL;
    int*   fill_rc  = fill;
    int*   fill_cr  = fill + NCOL;

    // ---- CSR build (shared by both layers) + bf16 feature tables ----
    hipMemsetAsync(hist8, 0, (size_t)NXCD * NTAB * sizeof(int), stream);
    hipMemsetAsync(fill, 0, 100000 * sizeof(int), stream);
    feats_to_bf16<<<2048, 256, 0, stream>>>((const float4*)feat_row, (const float4*)feat_col,
                                            (ushort4*)bf_row, (ushort4*)bf_col, NROW * 64 / 4);
    hist_local<<<2048, 256, 0, stream>>>(src_rc, dst_rc, src_cr, dst_cr, hist8, E);
    reduce_norms<<<512, 256, 0, stream>>>(hist8, cnt, norms);
    excl_scan2<<<2, 1024, 0, stream>>>(c_in_rc, ptr_rc, NCOL, c_in_cr, ptr_cr, NROW);
    csr_fill2<<<2048, 256, 0, stream>>>(src_rc, dst_rc, w_rc, r_out_rc, ptr_rc, fill_rc, pair_rc,
                                        src_cr, dst_cr, w_cr, r_out_cr, ptr_cr, fill_cr, pair_cr, E);

    // ---- layer 1 ----
    gather64_bf16<<<2048, 256, 0, stream>>>(bf_row, ptr_rc, pair_rc, agg_col, NCOL);
    dense_relu_k<64, false, true><<<2048, 128, 0, stream>>>(agg_col, r_in_rc_, W0_rc, b0_rc, h_col1, NCOL, 0.f);
    gather64_bf16<<<2048, 256, 0, stream>>>(bf_col, ptr_cr, pair_cr, agg_row, NROW);
    dense_relu_k<64, false, true><<<2048, 128, 0, stream>>>(agg_row, r_in_cr, W0_cr, b0_cr, h_row1, NROW, 0.f);

    hipMemsetAsync(out, 0, DH * sizeof(float), stream);

    // ---- layer 2 + fused mean pooling ----
    gather128_bf16<<<2048, 256, 0, stream>>>(h_row1, ptr_rc, pair_rc, agg_col, NCOL);
    dense_relu_k<128, true, false><<<1024, 128, 0, stream>>>(agg_col, r_in_rc_, W1_rc, b1_rc, out, NCOL, 1.0f / NCOL);
    gather128_bf16<<<2048, 256, 0, stream>>>(h_col1, ptr_cr, pair_cr, agg_row, NROW);
    dense_relu_k<128, true, false><<<1024, 128, 0, stream>>>(agg_row, r_in_cr, W1_cr, b1_cr, out, NROW, 1.0f / NROW);
}

// Round 6
// 683.709 us; speedup vs baseline: 9.6483x; 1.2150x over previous
//
#include <hip/hip_runtime.h>

constexpr int NROW = 50000;
constexpr int NCOL = 50000;
constexpr int DH   = 128;
constexpr int NTAB = 200000;   // [out_rc(NROW) | in_rc(NCOL) | out_cr(NCOL) | in_cr(NROW)]
constexpr int HB   = 25000;    // bins per section (half table), 100 KB LDS
constexpr int HBLK = 32;       // blocks per section; 8 sections * 32 = 256 blocks = 1/CU

__device__ __forceinline__ float bf_lo(unsigned u) { return __uint_as_float(u << 16); }
__device__ __forceinline__ float bf_hi(unsigned u) { return __uint_as_float(u & 0xffff0000u); }
__device__ __forceinline__ unsigned short f2bf(float f) {   // RNE
    unsigned u = __float_as_uint(f);
    return (unsigned short)((u + 0x7fffu + ((u >> 16) & 1u)) >> 16);
}

// ---- degree histograms via LDS privatization: NO global atomics ----
// grid: 8 sections (4 arrays x 2 bin-halves) x HBLK blocks, 512 threads
__global__ __launch_bounds__(512) void hist_lds(
        const int* __restrict__ s_rc, const int* __restrict__ d_rc,
        const int* __restrict__ s_cr, const int* __restrict__ d_cr,
        int* __restrict__ partial, int E) {
    __shared__ int h[HB];
    const int sec = blockIdx.x >> 5;          // 0..7
    const int blk = blockIdx.x & (HBLK - 1);
    const int tab = sec >> 1;                  // 0..3 -> array
    const int lo  = (sec & 1) * HB;
    const int* __restrict__ arr = (tab == 0) ? s_rc : (tab == 1) ? d_rc
                                 : (tab == 2) ? s_cr : d_cr;
    for (int i = threadIdx.x; i < HB; i += blockDim.x) h[i] = 0;
    __syncthreads();
    const int stride = HBLK * blockDim.x;
    for (int i = blk * blockDim.x + threadIdx.x; i < E; i += stride) {
        int id = arr[i] - lo;
        if ((unsigned)id < (unsigned)HB) atomicAdd(&h[id], 1);   // LDS atomic, CU-local
    }
    __syncthreads();
    int* __restrict__ out = partial + ((size_t)sec * HBLK + blk) * HB;
    for (int i = threadIdx.x; i < HB; i += blockDim.x) out[i] = h[i];  // plain stores
}

// ---- reduce 32 partials/section -> cnt + norms ----
__global__ void reduce_norms2(const int* __restrict__ partial, int* __restrict__ cnt,
                              float* __restrict__ norms) {
    int stride = gridDim.x * blockDim.x;
    for (int i = blockIdx.x * blockDim.x + threadIdx.x; i < NTAB; i += stride) {
        int t = i / 50000;
        int r = i - t * 50000;
        int hh = r / HB;
        int j = r - hh * HB;
        const int* __restrict__ p = partial + ((size_t)(t * 2 + hh) * HBLK) * HB + j;
        int s = 0;
#pragma unroll
        for (int b = 0; b < HBLK; ++b) s += p[(size_t)b * HB];
        cnt[i] = s;
        norms[i] = 1.0f / sqrtf((float)max(s, 1));
    }
}

// single-block segmented exclusive scan (1024 threads)
__device__ void scan_dev(const int* __restrict__ cnt, int* __restrict__ ptr, int n) {
    constexpr int NT = 1024;
    const int t = threadIdx.x;
    const int seg = (n + NT - 1) / NT;
    const int lo = t * seg, hi = min(lo + seg, n);
    int sum = 0;
    for (int i = lo; i < hi; ++i) sum += cnt[i];
    __shared__ int buf[NT];
    buf[t] = sum;
    __syncthreads();
    for (int off = 1; off < NT; off <<= 1) {
        int v = (t >= off) ? buf[t - off] : 0;
        __syncthreads();
        buf[t] += v;
        __syncthreads();
    }
    int run = buf[t] - sum;
    for (int i = lo; i < hi; ++i) { ptr[i] = run; run += cnt[i]; }
    if (t == NT - 1) ptr[n] = buf[NT - 1];
}

__global__ void excl_scan2(const int* cA, int* pA, int nA, const int* cB, int* pB, int nB) {
    if (blockIdx.x == 0) scan_dev(cA, pA, nA);
    else                 scan_dev(cB, pB, nB);
}

// fill CSR for both relations (grid split): pair[pos] = (src, w*rsqrt(outdeg[src]))
__global__ void csr_fill2(const int* __restrict__ srcA, const int* __restrict__ dstA,
                          const float* __restrict__ wA, const float* __restrict__ routA,
                          const int* __restrict__ ptrA, int* __restrict__ fillA, int2* __restrict__ pairA,
                          const int* __restrict__ srcB, const int* __restrict__ dstB,
                          const float* __restrict__ wB, const float* __restrict__ routB,
                          const int* __restrict__ ptrB, int* __restrict__ fillB, int2* __restrict__ pairB,
                          int E) {
    const int nb = gridDim.x >> 1;
    const bool second = blockIdx.x >= nb;
    const int bid = second ? blockIdx.x - nb : blockIdx.x;
    const int* __restrict__ src  = second ? srcB  : srcA;
    const int* __restrict__ dst  = second ? dstB  : dstA;
    const float* __restrict__ w  = second ? wB    : wA;
    const float* __restrict__ ro = second ? routB : routA;
    const int* __restrict__ ptr  = second ? ptrB  : ptrA;
    int* __restrict__ fill       = second ? fillB : fillA;
    int2* __restrict__ pair      = second ? pairB : pairA;
    const int stride = nb * blockDim.x;
    for (int i = bid * blockDim.x + threadIdx.x; i < E; i += stride) {
        int d = dst[i];
        int pos = ptr[d] + atomicAdd(&fill[d], 1);
        int s = src[i];
        pair[pos] = make_int2(s, __float_as_int(w[i] * ro[s]));
    }
}

// ---- fp32 -> bf16 feature tables (both in one launch) ----
__global__ void feats_to_bf16(const float4* __restrict__ fr, const float4* __restrict__ fc,
                              ushort4* __restrict__ br, ushort4* __restrict__ bc, int nq) {
    int stride = gridDim.x * blockDim.x;
    for (int i = blockIdx.x * blockDim.x + threadIdx.x; i < 2 * nq; i += stride) {
        bool second = i >= nq;
        int k = second ? i - nq : i;
        float4 v = second ? fc[k] : fr[k];
        ushort4 o;
        o.x = f2bf(v.x); o.y = f2bf(v.y); o.z = f2bf(v.z); o.w = f2bf(v.w);
        if (second) bc[k] = o; else br[k] = o;
    }
}

// ---- D=64 gather: full wave per node, 2 edges/iter (half-wave each), unroll 2 ----
__global__ void gather64_bf16(const unsigned short* __restrict__ h, const int* __restrict__ ptr,
                              const int2* __restrict__ pair, float* __restrict__ agg, int n) {
    const int gw   = (blockIdx.x * blockDim.x + threadIdx.x) >> 6;
    const int nw   = (gridDim.x * blockDim.x) >> 6;
    const int lane = threadIdx.x & 63;
    const int half = lane >> 5;
    const int c    = (lane & 31) << 1;          // column pair 0..62
    for (int node = gw; node < n; node += nw) {
        const int beg = ptr[node], end = ptr[node + 1];
        float ax0 = 0.f, ay0 = 0.f, ax1 = 0.f, ay1 = 0.f;
        int j = beg + half;
        for (; j + 2 < end; j += 4) {
            int2 p0 = pair[j], p1 = pair[j + 2];
            unsigned h0 = *reinterpret_cast<const unsigned*>(&h[(size_t)p0.x * 64 + c]);
            unsigned h1 = *reinterpret_cast<const unsigned*>(&h[(size_t)p1.x * 64 + c]);
            float w0 = __int_as_float(p0.y), w1 = __int_as_float(p1.y);
            ax0 = fmaf(bf_lo(h0), w0, ax0); ay0 = fmaf(bf_hi(h0), w0, ay0);
            ax1 = fmaf(bf_lo(h1), w1, ax1); ay1 = fmaf(bf_hi(h1), w1, ay1);
        }
        for (; j < end; j += 2) {
            int2 p = pair[j];
            unsigned hv = *reinterpret_cast<const unsigned*>(&h[(size_t)p.x * 64 + c]);
            float w = __int_as_float(p.y);
            ax0 = fmaf(bf_lo(hv), w, ax0); ay0 = fmaf(bf_hi(hv), w, ay0);
        }
        float ax = ax0 + ax1, ay = ay0 + ay1;
        ax += __shfl_xor(ax, 32);
        ay += __shfl_xor(ay, 32);
        if (half == 0) {
            float2 r; r.x = ax; r.y = ay;
            *reinterpret_cast<float2*>(&agg[(size_t)node * 64 + c]) = r;
        }
    }
}

// ---- D=128 gather: full wave per node, lane holds 2 bf16 cols, 2 edges in flight ----
__global__ void gather128_bf16(const unsigned short* __restrict__ h, const int* __restrict__ ptr,
                               const int2* __restrict__ pair, float* __restrict__ agg, int n) {
    const int gw   = (blockIdx.x * blockDim.x + threadIdx.x) >> 6;
    const int nw   = (gridDim.x * blockDim.x) >> 6;
    const int lane = threadIdx.x & 63;
    const int c    = lane << 1;                 // column pair 0..126
    for (int node = gw; node < n; node += nw) {
        const int beg = ptr[node], end = ptr[node + 1];
        float ax0 = 0.f, ay0 = 0.f, ax1 = 0.f, ay1 = 0.f;
        int j = beg;
        for (; j + 1 < end; j += 2) {
            int2 p0 = pair[j], p1 = pair[j + 1];
            unsigned h0 = *reinterpret_cast<const unsigned*>(&h[(size_t)p0.x * 128 + c]);
            unsigned h1 = *reinterpret_cast<const unsigned*>(&h[(size_t)p1.x * 128 + c]);
            float w0 = __int_as_float(p0.y), w1 = __int_as_float(p1.y);
            ax0 = fmaf(bf_lo(h0), w0, ax0); ay0 = fmaf(bf_hi(h0), w0, ay0);
            ax1 = fmaf(bf_lo(h1), w1, ax1); ay1 = fmaf(bf_hi(h1), w1, ay1);
        }
        if (j < end) {
            int2 p = pair[j];
            unsigned hv = *reinterpret_cast<const unsigned*>(&h[(size_t)p.x * 128 + c]);
            float w = __int_as_float(p.y);
            ax0 = fmaf(bf_lo(hv), w, ax0); ay0 = fmaf(bf_hi(hv), w, ay0);
        }
        float2 r; r.x = ax0 + ax1; r.y = ay0 + ay1;
        *reinterpret_cast<float2*>(&agg[(size_t)node * 128 + c]) = r;
    }
}

// ---- dense epilogue: relu(rin*(agg@W)+b); 8 nodes/iter; optional bf16 out / mean-pool ----
template <int K, bool MEANSUM, bool OUTBF16>
__global__ void dense_relu_k(const float* __restrict__ agg, const float* __restrict__ rin,
                             const float* __restrict__ W, const float* __restrict__ b,
                             void* __restrict__ outv, int n, float invn) {
    constexpr int NB = 8;
    constexpr int LOGK = (K == 64) ? 6 : 7;
    __shared__ float a[NB][K];
    const int t = threadIdx.x;                   // one output column each
    const float bias = b[t];
    float acc = 0.f;
    for (int base = blockIdx.x * NB; base < n; base += gridDim.x * NB) {
#pragma unroll
        for (int j = 0; j < NB * K / 128; ++j) {
            int idx = t + j * 128;
            int r = idx >> LOGK, c = idx & (K - 1);
            int node = base + r;
            a[r][c] = (node < n) ? agg[(size_t)node * K + c] : 0.f;
        }
        __syncthreads();
        float s[NB];
#pragma unroll
        for (int r = 0; r < NB; ++r) s[r] = 0.f;
#pragma unroll 4
        for (int k = 0; k < K; ++k) {
            const float wk = W[k * DH + t];
#pragma unroll
            for (int r = 0; r < NB; ++r) s[r] = fmaf(a[r][k], wk, s[r]);
        }
#pragma unroll
        for (int r = 0; r < NB; ++r) {
            const int node = base + r;
            if (node < n) {
                const float v = fmaxf(fmaf(rin[node], s[r], bias), 0.f);
                if (MEANSUM) acc += v;
                else if (OUTBF16) ((unsigned short*)outv)[(size_t)node * DH + t] = f2bf(v);
                else ((float*)outv)[(size_t)node * DH + t] = v;
            }
        }
        __syncthreads();
    }
    if (MEANSUM) atomicAdd(&((float*)outv)[t], acc * invn);
}

extern "C" void kernel_launch(void* const* d_in, const int* in_sizes, int n_in,
                              void* d_out, int out_size, void* d_ws, size_t ws_size,
                              hipStream_t stream) {
    const float* feat_row = (const float*)d_in[0];
    const float* feat_col = (const float*)d_in[1];
    const int*   src_rc   = (const int*)d_in[2];
    const int*   dst_rc   = (const int*)d_in[3];
    const float* w_rc     = (const float*)d_in[4];
    const int*   src_cr   = (const int*)d_in[5];
    const int*   dst_cr   = (const int*)d_in[6];
    const float* w_cr     = (const float*)d_in[7];
    const float* W0_rc    = (const float*)d_in[8];
    const float* b0_rc    = (const float*)d_in[9];
    const float* W0_cr    = (const float*)d_in[10];
    const float* b0_cr    = (const float*)d_in[11];
    const float* W1_rc    = (const float*)d_in[12];
    const float* b1_rc    = (const float*)d_in[13];
    const float* W1_cr    = (const float*)d_in[14];
    const float* b1_cr    = (const float*)d_in[15];
    const int E = in_sizes[2];
    float* out = (float*)d_out;

    // workspace layout (~111 MB); partial hist (25.6 MB) aliases the not-yet-live agg_col
    int*   cnt     = (int*)d_ws;                        // 200000
    int*   fill    = cnt + 200000;                      // 100000 [fill_rc|fill_cr]
    float* norms   = (float*)(fill + 100000);           // 200000 same order as cnt
    int*   ptr_rc  = (int*)(norms + 200000);            // 50004
    int*   ptr_cr  = ptr_rc + 50004;                    // 50004
    int2*  pair_rc = (int2*)(ptr_cr + 50004);           // E
    int2*  pair_cr = pair_rc + E;                       // E
    float* agg_col = (float*)(pair_cr + E);             // NCOL*128
    float* agg_row = agg_col + (size_t)NCOL * DH;       // NROW*128
    unsigned short* bf_row = (unsigned short*)(agg_row + (size_t)NROW * DH); // NROW*64
    unsigned short* bf_col = bf_row + (size_t)NROW * 64;                     // NCOL*64
    unsigned short* h_col1 = bf_col + (size_t)NCOL * 64;                     // NCOL*128
    unsigned short* h_row1 = h_col1 + (size_t)NCOL * DH;                     // NROW*128
    int*   partial = (int*)agg_col;                     // 8*HBLK*HB ints = 25.6 MB, dead before gathers

    float* r_out_rc = norms;
    float* r_in_rc  = norms + NROW;
    float* r_out_cr = norms + NROW + NCOL;
    float* r_in_cr  = norms + NROW + 2 * NCOL;
    int*   c_in_rc  = cnt + NROW;
    int*   c_in_cr  = cnt + NROW + 2 * NCOL;
    int*   fill_rc  = fill;
    int*   fill_cr  = fill + NCOL;

    // ---- CSR build (shared by both layers) + bf16 feature tables ----
    hipMemsetAsync(fill, 0, 100000 * sizeof(int), stream);
    feats_to_bf16<<<2048, 256, 0, stream>>>((const float4*)feat_row, (const float4*)feat_col,
                                            (ushort4*)bf_row, (ushort4*)bf_col, NROW * 64 / 4);
    hist_lds<<<8 * HBLK, 512, 0, stream>>>(src_rc, dst_rc, src_cr, dst_cr, partial, E);
    reduce_norms2<<<512, 256, 0, stream>>>(partial, cnt, norms);
    excl_scan2<<<2, 1024, 0, stream>>>(c_in_rc, ptr_rc, NCOL, c_in_cr, ptr_cr, NROW);
    csr_fill2<<<2048, 256, 0, stream>>>(src_rc, dst_rc, w_rc, r_out_rc, ptr_rc, fill_rc, pair_rc,
                                        src_cr, dst_cr, w_cr, r_out_cr, ptr_cr, fill_cr, pair_cr, E);

    // ---- layer 1 ----
    gather64_bf16<<<2048, 256, 0, stream>>>(bf_row, ptr_rc, pair_rc, agg_col, NCOL);
    dense_relu_k<64, false, true><<<2048, 128, 0, stream>>>(agg_col, r_in_rc, W0_rc, b0_rc, h_col1, NCOL, 0.f);
    gather64_bf16<<<2048, 256, 0, stream>>>(bf_col, ptr_cr, pair_cr, agg_row, NROW);
    dense_relu_k<64, false, true><<<2048, 128, 0, stream>>>(agg_row, r_in_cr, W0_cr, b0_cr, h_row1, NROW, 0.f);

    hipMemsetAsync(out, 0, DH * sizeof(float), stream);

    // ---- layer 2 + fused mean pooling ----
    gather128_bf16<<<2048, 256, 0, stream>>>(h_row1, ptr_rc, pair_rc, agg_col, NCOL);
    dense_relu_k<128, true, false><<<1024, 128, 0, stream>>>(agg_col, r_in_rc, W1_rc, b1_rc, out, NCOL, 1.0f / NCOL);
    gather128_bf16<<<2048, 256, 0, stream>>>(h_col1, ptr_cr, pair_cr, agg_row, NROW);
    dense_relu_k<128, true, false><<<1024, 128, 0, stream>>>(agg_row, r_in_cr, W1_cr, b1_cr, out, NROW, 1.0f / NROW);
}

// Round 7
// 629.222 us; speedup vs baseline: 10.4838x; 1.0866x over previous
//
#include <hip/hip_runtime.h>

constexpr int NROW = 50000;
constexpr int NCOL = 50000;
constexpr int DH   = 128;
constexpr int NTAB = 200000;   // [out_rc(NROW) | in_rc(NCOL) | out_cr(NCOL) | in_cr(NROW)]
constexpr int HB   = 25000;    // bins per section (half table), 100 KB LDS
constexpr int HBLK = 32;       // blocks per section

__device__ __forceinline__ float bf_lo(unsigned u) { return __uint_as_float(u << 16); }
__device__ __forceinline__ float bf_hi(unsigned u) { return __uint_as_float(u & 0xffff0000u); }
__device__ __forceinline__ unsigned short f2bf(float f) {   // RNE
    unsigned u = __float_as_uint(f);
    return (unsigned short)((u + 0x7fffu + ((u >> 16) & 1u)) >> 16);
}

// ---- degree histograms via LDS privatization: NO global atomics ----
// grid: 8 sections (4 arrays x 2 bin-halves) x HBLK blocks, 512 threads
__global__ __launch_bounds__(512) void hist_lds(
        const int* __restrict__ s_rc, const int* __restrict__ d_rc,
        const int* __restrict__ s_cr, const int* __restrict__ d_cr,
        int* __restrict__ partial, int E) {
    __shared__ int h[HB];
    const int sec = blockIdx.x >> 5;          // 0..7
    const int blk = blockIdx.x & (HBLK - 1);
    const int tab = sec >> 1;                  // 0..3 -> array
    const int lo  = (sec & 1) * HB;
    const int* __restrict__ arr = (tab == 0) ? s_rc : (tab == 1) ? d_rc
                                 : (tab == 2) ? s_cr : d_cr;
    for (int i = threadIdx.x; i < HB; i += blockDim.x) h[i] = 0;
    __syncthreads();
    const int stride = HBLK * blockDim.x;
    for (int i = blk * blockDim.x + threadIdx.x; i < E; i += stride) {
        int id = arr[i] - lo;
        if ((unsigned)id < (unsigned)HB) atomicAdd(&h[id], 1);   // LDS atomic, CU-local
    }
    __syncthreads();
    int* __restrict__ out = partial + ((size_t)sec * HBLK + blk) * HB;
    for (int i = threadIdx.x; i < HB; i += blockDim.x) out[i] = h[i];  // plain stores
}

// ---- reduce 32 partials/section -> cnt + norms (must run BEFORE block_starts) ----
__global__ void reduce_norms2(const int* __restrict__ partial, int* __restrict__ cnt,
                              float* __restrict__ norms) {
    int stride = gridDim.x * blockDim.x;
    for (int i = blockIdx.x * blockDim.x + threadIdx.x; i < NTAB; i += stride) {
        int t = i / 50000;
        int r = i - t * 50000;
        int hh = r / HB;
        int j = r - hh * HB;
        const int* __restrict__ p = partial + ((size_t)(t * 2 + hh) * HBLK) * HB + j;
        int s = 0;
#pragma unroll
        for (int b = 0; b < HBLK; ++b) s += p[(size_t)b * HB];
        cnt[i] = s;
        norms[i] = 1.0f / sqrtf((float)max(s, 1));
    }
}

// single-block segmented exclusive scan (1024 threads)
__device__ void scan_dev(const int* __restrict__ cnt, int* __restrict__ ptr, int n) {
    constexpr int NT = 1024;
    const int t = threadIdx.x;
    const int seg = (n + NT - 1) / NT;
    const int lo = t * seg, hi = min(lo + seg, n);
    int sum = 0;
    for (int i = lo; i < hi; ++i) sum += cnt[i];
    __shared__ int buf[NT];
    buf[t] = sum;
    __syncthreads();
    for (int off = 1; off < NT; off <<= 1) {
        int v = (t >= off) ? buf[t - off] : 0;
        __syncthreads();
        buf[t] += v;
        __syncthreads();
    }
    int run = buf[t] - sum;
    for (int i = lo; i < hi; ++i) { ptr[i] = run; run += cnt[i]; }
    if (t == NT - 1) ptr[n] = buf[NT - 1];
}

__global__ void excl_scan2(const int* cA, int* pA, int nA, const int* cB, int* pB, int nB) {
    if (blockIdx.x == 0) scan_dev(cA, pA, nA);
    else                 scan_dev(cB, pB, nB);
}

// ---- convert dst-section partials in place to absolute block start positions:
//      partial[sec][blk][bin] = ptr[bin] + sum_{b<blk} partial[sec][b][bin]
__global__ void block_starts(int* __restrict__ partial,
                             const int* __restrict__ ptr_rc, const int* __restrict__ ptr_cr) {
    int stride = gridDim.x * blockDim.x;
    for (int i = blockIdx.x * blockDim.x + threadIdx.x; i < 4 * HB; i += stride) {
        int fsec = i / HB;                 // 0..3 = (rel, half)
        int j = i - fsec * HB;
        int rel = fsec >> 1, half = fsec & 1;
        int histsec = (rel ? 6 : 2) + half;
        const int* __restrict__ ptr = rel ? ptr_cr : ptr_rc;
        int run = ptr[half * HB + j];
        int* __restrict__ p = partial + ((size_t)histsec * HBLK) * HB + j;
#pragma unroll
        for (int b = 0; b < HBLK; ++b) {
            int c = p[(size_t)b * HB];
            p[(size_t)b * HB] = run;
            run += c;
        }
    }
}

// ---- CSR fill, atomic-free (LDS offsets), 4-byte packed pair: u16 src | bf16 w<<16 ----
// grid: 4 sections (2 relations x 2 dst-halves) x HBLK blocks, 512 threads.
// MUST traverse edges exactly like hist_lds so counts match block starts.
__global__ __launch_bounds__(512) void csr_fill_sorted(
        const int* __restrict__ sA, const int* __restrict__ dA,
        const float* __restrict__ wA, const float* __restrict__ routA, unsigned* __restrict__ pairA,
        const int* __restrict__ sB, const int* __restrict__ dB,
        const float* __restrict__ wB, const float* __restrict__ routB, unsigned* __restrict__ pairB,
        const int* __restrict__ partial, int E) {
    __shared__ int offs[HB];
    const int fsec = blockIdx.x >> 5;
    const int blk  = blockIdx.x & (HBLK - 1);
    const int rel = fsec >> 1, half = fsec & 1;
    const int histsec = (rel ? 6 : 2) + half;
    const int lo = half * HB;
    const int* __restrict__ src  = rel ? sB : sA;
    const int* __restrict__ dst  = rel ? dB : dA;
    const float* __restrict__ w  = rel ? wB : wA;
    const float* __restrict__ ro = rel ? routB : routA;
    unsigned* __restrict__ pair  = rel ? pairB : pairA;
    const int* __restrict__ bs = partial + ((size_t)histsec * HBLK + blk) * HB;
    for (int i = threadIdx.x; i < HB; i += blockDim.x) offs[i] = bs[i];
    __syncthreads();
    const int stride = HBLK * blockDim.x;
    for (int i = blk * blockDim.x + threadIdx.x; i < E; i += stride) {
        int id = dst[i] - lo;
        if ((unsigned)id < (unsigned)HB) {
            int pos = atomicAdd(&offs[id], 1);            // LDS atomic
            int s = src[i];
            pair[pos] = (unsigned)s | ((unsigned)f2bf(w[i] * ro[s]) << 16);
        }
    }
}

// ---- fp32 -> bf16 feature tables (both in one launch) ----
__global__ void feats_to_bf16(const float4* __restrict__ fr, const float4* __restrict__ fc,
                              ushort4* __restrict__ br, ushort4* __restrict__ bc, int nq) {
    int stride = gridDim.x * blockDim.x;
    for (int i = blockIdx.x * blockDim.x + threadIdx.x; i < 2 * nq; i += stride) {
        bool second = i >= nq;
        int k = second ? i - nq : i;
        float4 v = second ? fc[k] : fr[k];
        ushort4 o;
        o.x = f2bf(v.x); o.y = f2bf(v.y); o.z = f2bf(v.z); o.w = f2bf(v.w);
        if (second) bc[k] = o; else br[k] = o;
    }
}

// ---- D=64 gather: full wave per node, 2 edges/iter (half-wave each), unroll 2 ----
__global__ void gather64_bf16(const unsigned short* __restrict__ h, const int* __restrict__ ptr,
                              const unsigned* __restrict__ pair, float* __restrict__ agg, int n) {
    const int gw   = (blockIdx.x * blockDim.x + threadIdx.x) >> 6;
    const int nw   = (gridDim.x * blockDim.x) >> 6;
    const int lane = threadIdx.x & 63;
    const int half = lane >> 5;
    const int c    = (lane & 31) << 1;          // column pair 0..62
    for (int node = gw; node < n; node += nw) {
        const int beg = ptr[node], end = ptr[node + 1];
        float ax0 = 0.f, ay0 = 0.f, ax1 = 0.f, ay1 = 0.f;
        int j = beg + half;
        for (; j + 2 < end; j += 4) {
            unsigned p0 = pair[j], p1 = pair[j + 2];
            unsigned h0 = *reinterpret_cast<const unsigned*>(&h[(size_t)(p0 & 0xffffu) * 64 + c]);
            unsigned h1 = *reinterpret_cast<const unsigned*>(&h[(size_t)(p1 & 0xffffu) * 64 + c]);
            float w0 = bf_hi(p0), w1 = bf_hi(p1);
            ax0 = fmaf(bf_lo(h0), w0, ax0); ay0 = fmaf(bf_hi(h0), w0, ay0);
            ax1 = fmaf(bf_lo(h1), w1, ax1); ay1 = fmaf(bf_hi(h1), w1, ay1);
        }
        for (; j < end; j += 2) {
            unsigned p = pair[j];
            unsigned hv = *reinterpret_cast<const unsigned*>(&h[(size_t)(p & 0xffffu) * 64 + c]);
            float w = bf_hi(p);
            ax0 = fmaf(bf_lo(hv), w, ax0); ay0 = fmaf(bf_hi(hv), w, ay0);
        }
        float ax = ax0 + ax1, ay = ay0 + ay1;
        ax += __shfl_xor(ax, 32);
        ay += __shfl_xor(ay, 32);
        if (half == 0) {
            float2 r; r.x = ax; r.y = ay;
            *reinterpret_cast<float2*>(&agg[(size_t)node * 64 + c]) = r;
        }
    }
}

// ---- D=128 gather: full wave per node, lane holds 2 bf16 cols, 2 edges in flight ----
__global__ void gather128_bf16(const unsigned short* __restrict__ h, const int* __restrict__ ptr,
                               const unsigned* __restrict__ pair, float* __restrict__ agg, int n) {
    const int gw   = (blockIdx.x * blockDim.x + threadIdx.x) >> 6;
    const int nw   = (gridDim.x * blockDim.x) >> 6;
    const int lane = threadIdx.x & 63;
    const int c    = lane << 1;                 // column pair 0..126
    for (int node = gw; node < n; node += nw) {
        const int beg = ptr[node], end = ptr[node + 1];
        float ax0 = 0.f, ay0 = 0.f, ax1 = 0.f, ay1 = 0.f;
        int j = beg;
        for (; j + 1 < end; j += 2) {
            unsigned p0 = pair[j], p1 = pair[j + 1];
            unsigned h0 = *reinterpret_cast<const unsigned*>(&h[(size_t)(p0 & 0xffffu) * 128 + c]);
            unsigned h1 = *reinterpret_cast<const unsigned*>(&h[(size_t)(p1 & 0xffffu) * 128 + c]);
            float w0 = bf_hi(p0), w1 = bf_hi(p1);
            ax0 = fmaf(bf_lo(h0), w0, ax0); ay0 = fmaf(bf_hi(h0), w0, ay0);
            ax1 = fmaf(bf_lo(h1), w1, ax1); ay1 = fmaf(bf_hi(h1), w1, ay1);
        }
        if (j < end) {
            unsigned p = pair[j];
            unsigned hv = *reinterpret_cast<const unsigned*>(&h[(size_t)(p & 0xffffu) * 128 + c]);
            float w = bf_hi(p);
            ax0 = fmaf(bf_lo(hv), w, ax0); ay0 = fmaf(bf_hi(hv), w, ay0);
        }
        float2 r; r.x = ax0 + ax1; r.y = ay0 + ay1;
        *reinterpret_cast<float2*>(&agg[(size_t)node * 128 + c]) = r;
    }
}

// ---- dense epilogue: relu(rin*(agg@W)+b); 8 nodes/iter; optional bf16 out / mean-pool ----
template <int K, bool MEANSUM, bool OUTBF16>
__global__ void dense_relu_k(const float* __restrict__ agg, const float* __restrict__ rin,
                             const float* __restrict__ W, const float* __restrict__ b,
                             void* __restrict__ outv, int n, float invn) {
    constexpr int NB = 8;
    constexpr int LOGK = (K == 64) ? 6 : 7;
    __shared__ float a[NB][K];
    const int t = threadIdx.x;                   // one output column each
    const float bias = b[t];
    float acc = 0.f;
    for (int base = blockIdx.x * NB; base < n; base += gridDim.x * NB) {
#pragma unroll
        for (int j = 0; j < NB * K / 128; ++j) {
            int idx = t + j * 128;
            int r = idx >> LOGK, c = idx & (K - 1);
            int node = base + r;
            a[r][c] = (node < n) ? agg[(size_t)node * K + c] : 0.f;
        }
        __syncthreads();
        float s[NB];
#pragma unroll
        for (int r = 0; r < NB; ++r) s[r] = 0.f;
#pragma unroll 4
        for (int k = 0; k < K; ++k) {
            const float wk = W[k * DH + t];
#pragma unroll
            for (int r = 0; r < NB; ++r) s[r] = fmaf(a[r][k], wk, s[r]);
        }
#pragma unroll
        for (int r = 0; r < NB; ++r) {
            const int node = base + r;
            if (node < n) {
                const float v = fmaxf(fmaf(rin[node], s[r], bias), 0.f);
                if (MEANSUM) acc += v;
                else if (OUTBF16) ((unsigned short*)outv)[(size_t)node * DH + t] = f2bf(v);
                else ((float*)outv)[(size_t)node * DH + t] = v;
            }
        }
        __syncthreads();
    }
    if (MEANSUM) atomicAdd(&((float*)outv)[t], acc * invn);
}

extern "C" void kernel_launch(void* const* d_in, const int* in_sizes, int n_in,
                              void* d_out, int out_size, void* d_ws, size_t ws_size,
                              hipStream_t stream) {
    const float* feat_row = (const float*)d_in[0];
    const float* feat_col = (const float*)d_in[1];
    const int*   src_rc   = (const int*)d_in[2];
    const int*   dst_rc   = (const int*)d_in[3];
    const float* w_rc     = (const float*)d_in[4];
    const int*   src_cr   = (const int*)d_in[5];
    const int*   dst_cr   = (const int*)d_in[6];
    const float* w_cr     = (const float*)d_in[7];
    const float* W0_rc    = (const float*)d_in[8];
    const float* b0_rc    = (const float*)d_in[9];
    const float* W0_cr    = (const float*)d_in[10];
    const float* b0_cr    = (const float*)d_in[11];
    const float* W1_rc    = (const float*)d_in[12];
    const float* b1_rc    = (const float*)d_in[13];
    const float* W1_cr    = (const float*)d_in[14];
    const float* b1_cr    = (const float*)d_in[15];
    const int E = in_sizes[2];
    float* out = (float*)d_out;

    // workspace layout (~101 MB); partial hist (25.6 MB) aliases the not-yet-live agg_col
    int*   cnt     = (int*)d_ws;                        // 200000
    float* norms   = (float*)(cnt + 200000);            // 200000 same order as cnt
    int*   ptr_rc  = (int*)(norms + 200000);            // 50004
    int*   ptr_cr  = ptr_rc + 50004;                    // 50004
    unsigned* pair_rc = (unsigned*)(ptr_cr + 50004);    // E (4-byte packed)
    unsigned* pair_cr = pair_rc + E;                    // E
    float* agg_col = (float*)(pair_cr + E);             // NCOL*128
    float* agg_row = agg_col + (size_t)NCOL * DH;       // NROW*128
    unsigned short* bf_row = (unsigned short*)(agg_row + (size_t)NROW * DH); // NROW*64
    unsigned short* bf_col = bf_row + (size_t)NROW * 64;                     // NCOL*64
    unsigned short* h_col1 = bf_col + (size_t)NCOL * 64;                     // NCOL*128
    unsigned short* h_row1 = h_col1 + (size_t)NCOL * DH;                     // NROW*128
    int*   partial = (int*)agg_col;                     // 8*HBLK*HB ints = 25.6 MB, dead before gathers

    float* r_out_rc = norms;
    float* r_in_rc  = norms + NROW;
    float* r_out_cr = norms + NROW + NCOL;
    float* r_in_cr  = norms + NROW + 2 * NCOL;
    int*   c_in_rc  = cnt + NROW;
    int*   c_in_cr  = cnt + NROW + 2 * NCOL;

    // ---- CSR build (shared by both layers) + bf16 feature tables ----
    feats_to_bf16<<<2048, 256, 0, stream>>>((const float4*)feat_row, (const float4*)feat_col,
                                            (ushort4*)bf_row, (ushort4*)bf_col, NROW * 64 / 4);
    hist_lds<<<8 * HBLK, 512, 0, stream>>>(src_rc, dst_rc, src_cr, dst_cr, partial, E);
    reduce_norms2<<<512, 256, 0, stream>>>(partial, cnt, norms);
    excl_scan2<<<2, 1024, 0, stream>>>(c_in_rc, ptr_rc, NCOL, c_in_cr, ptr_cr, NROW);
    block_starts<<<400, 256, 0, stream>>>(partial, ptr_rc, ptr_cr);
    csr_fill_sorted<<<4 * HBLK, 512, 0, stream>>>(
        src_rc, dst_rc, w_rc, r_out_rc, pair_rc,
        src_cr, dst_cr, w_cr, r_out_cr, pair_cr, partial, E);

    // ---- layer 1 ----
    gather64_bf16<<<2048, 256, 0, stream>>>(bf_row, ptr_rc, pair_rc, agg_col, NCOL);
    dense_relu_k<64, false, true><<<2048, 128, 0, stream>>>(agg_col, r_in_rc, W0_rc, b0_rc, h_col1, NCOL, 0.f);
    gather64_bf16<<<2048, 256, 0, stream>>>(bf_col, ptr_cr, pair_cr, agg_row, NROW);
    dense_relu_k<64, false, true><<<2048, 128, 0, stream>>>(agg_row, r_in_cr, W0_cr, b0_cr, h_row1, NROW, 0.f);

    hipMemsetAsync(out, 0, DH * sizeof(float), stream);

    // ---- layer 2 + fused mean pooling ----
    gather128_bf16<<<2048, 256, 0, stream>>>(h_row1, ptr_rc, pair_rc, agg_col, NCOL);
    dense_relu_k<128, true, false><<<1024, 128, 0, stream>>>(agg_col, r_in_rc, W1_rc, b1_rc, out, NCOL, 1.0f / NCOL);
    gather128_bf16<<<2048, 256, 0, stream>>>(h_col1, ptr_cr, pair_cr, agg_row, NROW);
    dense_relu_k<128, true, false><<<1024, 128, 0, stream>>>(agg_row, r_in_cr, W1_cr, b1_cr, out, NROW, 1.0f / NROW);
}

// Round 8
// 585.414 us; speedup vs baseline: 11.2683x; 1.0748x over previous
//
#include <hip/hip_runtime.h>

constexpr int NROW = 50000;
constexpr int NCOL = 50000;
constexpr int DH   = 128;
constexpr int NTAB = 200000;   // [out_rc(NROW) | in_rc(NCOL) | out_cr(NCOL) | in_cr(NROW)]
constexpr int HB   = 12500;    // bins per section (quarter table), 50 KB LDS
constexpr int HBLK = 64;       // blocks per section

__device__ __forceinline__ float bf_lo(unsigned u) { return __uint_as_float(u << 16); }
__device__ __forceinline__ float bf_hi(unsigned u) { return __uint_as_float(u & 0xffff0000u); }
__device__ __forceinline__ unsigned short f2bf(float f) {   // RNE
    unsigned u = __float_as_uint(f);
    return (unsigned short)((u + 0x7fffu + ((u >> 16) & 1u)) >> 16);
}

// ---- degree histograms via LDS privatization: NO global atomics ----
// grid: 16 sections (4 arrays x 4 quarters) x HBLK blocks, 512 threads
__global__ __launch_bounds__(512) void hist_lds(
        const int* __restrict__ s_rc, const int* __restrict__ d_rc,
        const int* __restrict__ s_cr, const int* __restrict__ d_cr,
        int* __restrict__ partial, int E) {
    __shared__ int h[HB];
    const int sec = blockIdx.x >> 6;           // 0..15
    const int blk = blockIdx.x & (HBLK - 1);
    const int tab = sec >> 2;                  // 0..3 -> array
    const int lo  = (sec & 3) * HB;
    const int* __restrict__ arr = (tab == 0) ? s_rc : (tab == 1) ? d_rc
                                 : (tab == 2) ? s_cr : d_cr;
    for (int i = threadIdx.x; i < HB; i += blockDim.x) h[i] = 0;
    __syncthreads();
    const int stride = HBLK * blockDim.x;
    for (int i = blk * blockDim.x + threadIdx.x; i < E; i += stride) {
        int id = arr[i] - lo;
        if ((unsigned)id < (unsigned)HB) atomicAdd(&h[id], 1);   // LDS atomic, CU-local
    }
    __syncthreads();
    int* __restrict__ out = partial + ((size_t)sec * HBLK + blk) * HB;
    for (int i = threadIdx.x; i < HB; i += blockDim.x) out[i] = h[i];  // plain stores
}

// ---- reduce HBLK partials/section -> cnt + norms ----
__global__ void reduce_norms2(const int* __restrict__ partial, int* __restrict__ cnt,
                              float* __restrict__ norms) {
    int stride = gridDim.x * blockDim.x;
    for (int i = blockIdx.x * blockDim.x + threadIdx.x; i < NTAB; i += stride) {
        int t = i / 50000;
        int r = i - t * 50000;
        int q = r / HB;
        int j = r - q * HB;
        const int* __restrict__ p = partial + ((size_t)(t * 4 + q) * HBLK) * HB + j;
        int s = 0;
#pragma unroll
        for (int b = 0; b < HBLK; ++b) s += p[(size_t)b * HB];
        cnt[i] = s;
        norms[i] = 1.0f / sqrtf((float)max(s, 1));
    }
}

// single-block segmented exclusive scan (1024 threads)
__device__ void scan_dev(const int* __restrict__ cnt, int* __restrict__ ptr, int n) {
    constexpr int NT = 1024;
    const int t = threadIdx.x;
    const int seg = (n + NT - 1) / NT;
    const int lo = t * seg, hi = min(lo + seg, n);
    int sum = 0;
    for (int i = lo; i < hi; ++i) sum += cnt[i];
    __shared__ int buf[NT];
    buf[t] = sum;
    __syncthreads();
    for (int off = 1; off < NT; off <<= 1) {
        int v = (t >= off) ? buf[t - off] : 0;
        __syncthreads();
        buf[t] += v;
        __syncthreads();
    }
    int run = buf[t] - sum;
    for (int i = lo; i < hi; ++i) { ptr[i] = run; run += cnt[i]; }
    if (t == NT - 1) ptr[n] = buf[NT - 1];
}

__global__ void excl_scan2(const int* cA, int* pA, int nA, const int* cB, int* pB, int nB) {
    if (blockIdx.x == 0) scan_dev(cA, pA, nA);
    else                 scan_dev(cB, pB, nB);
}

// ---- convert dst-section partials in place to absolute block start positions:
//      partial[sec][blk][bin] = ptr[bin] + sum_{b<blk} partial[sec][b][bin]
__global__ void block_starts(int* __restrict__ partial,
                             const int* __restrict__ ptr_rc, const int* __restrict__ ptr_cr) {
    int stride = gridDim.x * blockDim.x;
    for (int i = blockIdx.x * blockDim.x + threadIdx.x; i < 8 * HB; i += stride) {
        int fsec = i / HB;                 // 0..7 = (rel, quarter)
        int j = i - fsec * HB;
        int rel = fsec >> 2, q = fsec & 3;
        int histsec = rel * 8 + 4 + q;     // tab=(rel*2+1), histsec = tab*4+q
        const int* __restrict__ ptr = rel ? ptr_cr : ptr_rc;
        int run = ptr[q * HB + j];
        int* __restrict__ p = partial + ((size_t)histsec * HBLK) * HB + j;
#pragma unroll
        for (int b = 0; b < HBLK; ++b) {
            int c = p[(size_t)b * HB];
            p[(size_t)b * HB] = run;
            run += c;
        }
    }
}

// ---- CSR fill, atomic-free (LDS offsets), 4-byte packed pair: u16 src | bf16 w<<16 ----
// grid: 8 sections (2 relations x 4 dst-quarters) x HBLK blocks, 512 threads.
// MUST traverse edges exactly like hist_lds so counts match block starts.
__global__ __launch_bounds__(512) void csr_fill_sorted(
        const int* __restrict__ sA, const int* __restrict__ dA,
        const float* __restrict__ wA, const float* __restrict__ routA, unsigned* __restrict__ pairA,
        const int* __restrict__ sB, const int* __restrict__ dB,
        const float* __restrict__ wB, const float* __restrict__ routB, unsigned* __restrict__ pairB,
        const int* __restrict__ partial, int E) {
    __shared__ int offs[HB];
    const int fsec = blockIdx.x >> 6;
    const int blk  = blockIdx.x & (HBLK - 1);
    const int rel = fsec >> 2, q = fsec & 3;
    const int histsec = rel * 8 + 4 + q;
    const int lo = q * HB;
    const int* __restrict__ src  = rel ? sB : sA;
    const int* __restrict__ dst  = rel ? dB : dA;
    const float* __restrict__ w  = rel ? wB : wA;
    const float* __restrict__ ro = rel ? routB : routA;
    unsigned* __restrict__ pair  = rel ? pairB : pairA;
    const int* __restrict__ bs = partial + ((size_t)histsec * HBLK + blk) * HB;
    for (int i = threadIdx.x; i < HB; i += blockDim.x) offs[i] = bs[i];
    __syncthreads();
    const int stride = HBLK * blockDim.x;
    for (int i = blk * blockDim.x + threadIdx.x; i < E; i += stride) {
        int id = dst[i] - lo;
        if ((unsigned)id < (unsigned)HB) {
            int pos = atomicAdd(&offs[id], 1);            // LDS atomic
            int s = src[i];
            pair[pos] = (unsigned)s | ((unsigned)f2bf(w[i] * ro[s]) << 16);
        }
    }
}

// ---- fp32 -> bf16 feature tables (both in one launch) ----
__global__ void feats_to_bf16(const float4* __restrict__ fr, const float4* __restrict__ fc,
                              ushort4* __restrict__ br, ushort4* __restrict__ bc, int nq) {
    int stride = gridDim.x * blockDim.x;
    for (int i = blockIdx.x * blockDim.x + threadIdx.x; i < 2 * nq; i += stride) {
        bool second = i >= nq;
        int k = second ? i - nq : i;
        float4 v = second ? fc[k] : fr[k];
        ushort4 o;
        o.x = f2bf(v.x); o.y = f2bf(v.y); o.z = f2bf(v.z); o.w = f2bf(v.w);
        if (second) bc[k] = o; else br[k] = o;
    }
}

// ---- D=64 gather: full wave per node, halves interleave edges, 4 edges/half in flight ----
__global__ void gather64_bf16(const unsigned short* __restrict__ h, const int* __restrict__ ptr,
                              const unsigned* __restrict__ pair, float* __restrict__ agg, int n) {
    const int gw   = (blockIdx.x * blockDim.x + threadIdx.x) >> 6;
    const int nw   = (gridDim.x * blockDim.x) >> 6;
    const int lane = threadIdx.x & 63;
    const int half = lane >> 5;
    const int c    = (lane & 31) << 1;          // column pair 0..62
    for (int node = gw; node < n; node += nw) {
        const int beg = ptr[node], end = ptr[node + 1];
        float ax0 = 0.f, ay0 = 0.f, ax1 = 0.f, ay1 = 0.f;
        float ax2 = 0.f, ay2 = 0.f, ax3 = 0.f, ay3 = 0.f;
        int j = beg + half;
        for (; j + 6 < end; j += 8) {
            unsigned p0 = pair[j], p1 = pair[j + 2], p2 = pair[j + 4], p3 = pair[j + 6];
            unsigned h0 = *reinterpret_cast<const unsigned*>(&h[(size_t)(p0 & 0xffffu) * 64 + c]);
            unsigned h1 = *reinterpret_cast<const unsigned*>(&h[(size_t)(p1 & 0xffffu) * 64 + c]);
            unsigned h2 = *reinterpret_cast<const unsigned*>(&h[(size_t)(p2 & 0xffffu) * 64 + c]);
            unsigned h3 = *reinterpret_cast<const unsigned*>(&h[(size_t)(p3 & 0xffffu) * 64 + c]);
            float w0 = bf_hi(p0), w1 = bf_hi(p1), w2 = bf_hi(p2), w3 = bf_hi(p3);
            ax0 = fmaf(bf_lo(h0), w0, ax0); ay0 = fmaf(bf_hi(h0), w0, ay0);
            ax1 = fmaf(bf_lo(h1), w1, ax1); ay1 = fmaf(bf_hi(h1), w1, ay1);
            ax2 = fmaf(bf_lo(h2), w2, ax2); ay2 = fmaf(bf_hi(h2), w2, ay2);
            ax3 = fmaf(bf_lo(h3), w3, ax3); ay3 = fmaf(bf_hi(h3), w3, ay3);
        }
        for (; j < end; j += 2) {
            unsigned p = pair[j];
            unsigned hv = *reinterpret_cast<const unsigned*>(&h[(size_t)(p & 0xffffu) * 64 + c]);
            float w = bf_hi(p);
            ax0 = fmaf(bf_lo(hv), w, ax0); ay0 = fmaf(bf_hi(hv), w, ay0);
        }
        float ax = (ax0 + ax1) + (ax2 + ax3);
        float ay = (ay0 + ay1) + (ay2 + ay3);
        ax += __shfl_xor(ax, 32);
        ay += __shfl_xor(ay, 32);
        if (half == 0) {
            float2 r; r.x = ax; r.y = ay;
            *reinterpret_cast<float2*>(&agg[(size_t)node * 64 + c]) = r;
        }
    }
}

// ---- D=128 gather: full wave per node, lane holds 2 bf16 cols, 4 edges in flight ----
__global__ void gather128_bf16(const unsigned short* __restrict__ h, const int* __restrict__ ptr,
                               const unsigned* __restrict__ pair, float* __restrict__ agg, int n) {
    const int gw   = (blockIdx.x * blockDim.x + threadIdx.x) >> 6;
    const int nw   = (gridDim.x * blockDim.x) >> 6;
    const int lane = threadIdx.x & 63;
    const int c    = lane << 1;                 // column pair 0..126
    for (int node = gw; node < n; node += nw) {
        const int beg = ptr[node], end = ptr[node + 1];
        float ax0 = 0.f, ay0 = 0.f, ax1 = 0.f, ay1 = 0.f;
        float ax2 = 0.f, ay2 = 0.f, ax3 = 0.f, ay3 = 0.f;
        int j = beg;
        for (; j + 3 < end; j += 4) {
            unsigned p0 = pair[j], p1 = pair[j + 1], p2 = pair[j + 2], p3 = pair[j + 3];
            unsigned h0 = *reinterpret_cast<const unsigned*>(&h[(size_t)(p0 & 0xffffu) * 128 + c]);
            unsigned h1 = *reinterpret_cast<const unsigned*>(&h[(size_t)(p1 & 0xffffu) * 128 + c]);
            unsigned h2 = *reinterpret_cast<const unsigned*>(&h[(size_t)(p2 & 0xffffu) * 128 + c]);
            unsigned h3 = *reinterpret_cast<const unsigned*>(&h[(size_t)(p3 & 0xffffu) * 128 + c]);
            float w0 = bf_hi(p0), w1 = bf_hi(p1), w2 = bf_hi(p2), w3 = bf_hi(p3);
            ax0 = fmaf(bf_lo(h0), w0, ax0); ay0 = fmaf(bf_hi(h0), w0, ay0);
            ax1 = fmaf(bf_lo(h1), w1, ax1); ay1 = fmaf(bf_hi(h1), w1, ay1);
            ax2 = fmaf(bf_lo(h2), w2, ax2); ay2 = fmaf(bf_hi(h2), w2, ay2);
            ax3 = fmaf(bf_lo(h3), w3, ax3); ay3 = fmaf(bf_hi(h3), w3, ay3);
        }
        for (; j < end; ++j) {
            unsigned p = pair[j];
            unsigned hv = *reinterpret_cast<const unsigned*>(&h[(size_t)(p & 0xffffu) * 128 + c]);
            float w = bf_hi(p);
            ax0 = fmaf(bf_lo(hv), w, ax0); ay0 = fmaf(bf_hi(hv), w, ay0);
        }
        float2 r;
        r.x = (ax0 + ax1) + (ax2 + ax3);
        r.y = (ay0 + ay1) + (ay2 + ay3);
        *reinterpret_cast<float2*>(&agg[(size_t)node * 128 + c]) = r;
    }
}

// ---- dense epilogue: relu(rin*(agg@W)+b); 8 nodes/iter; optional bf16 out / mean-pool ----
template <int K, bool MEANSUM, bool OUTBF16>
__global__ void dense_relu_k(const float* __restrict__ agg, const float* __restrict__ rin,
                             const float* __restrict__ W, const float* __restrict__ b,
                             void* __restrict__ outv, int n, float invn) {
    constexpr int NB = 8;
    constexpr int LOGK = (K == 64) ? 6 : 7;
    __shared__ float a[NB][K];
    const int t = threadIdx.x;                   // one output column each
    const float bias = b[t];
    float acc = 0.f;
    for (int base = blockIdx.x * NB; base < n; base += gridDim.x * NB) {
#pragma unroll
        for (int j = 0; j < NB * K / 128; ++j) {
            int idx = t + j * 128;
            int r = idx >> LOGK, c = idx & (K - 1);
            int node = base + r;
            a[r][c] = (node < n) ? agg[(size_t)node * K + c] : 0.f;
        }
        __syncthreads();
        float s[NB];
#pragma unroll
        for (int r = 0; r < NB; ++r) s[r] = 0.f;
#pragma unroll 4
        for (int k = 0; k < K; ++k) {
            const float wk = W[k * DH + t];
#pragma unroll
            for (int r = 0; r < NB; ++r) s[r] = fmaf(a[r][k], wk, s[r]);
        }
#pragma unroll
        for (int r = 0; r < NB; ++r) {
            const int node = base + r;
            if (node < n) {
                const float v = fmaxf(fmaf(rin[node], s[r], bias), 0.f);
                if (MEANSUM) acc += v;
                else if (OUTBF16) ((unsigned short*)outv)[(size_t)node * DH + t] = f2bf(v);
                else ((float*)outv)[(size_t)node * DH + t] = v;
            }
        }
        __syncthreads();
    }
    if (MEANSUM) atomicAdd(&((float*)outv)[t], acc * invn);
}

extern "C" void kernel_launch(void* const* d_in, const int* in_sizes, int n_in,
                              void* d_out, int out_size, void* d_ws, size_t ws_size,
                              hipStream_t stream) {
    const float* feat_row = (const float*)d_in[0];
    const float* feat_col = (const float*)d_in[1];
    const int*   src_rc   = (const int*)d_in[2];
    const int*   dst_rc   = (const int*)d_in[3];
    const float* w_rc     = (const float*)d_in[4];
    const int*   src_cr   = (const int*)d_in[5];
    const int*   dst_cr   = (const int*)d_in[6];
    const float* w_cr     = (const float*)d_in[7];
    const float* W0_rc    = (const float*)d_in[8];
    const float* b0_rc    = (const float*)d_in[9];
    const float* W0_cr    = (const float*)d_in[10];
    const float* b0_cr    = (const float*)d_in[11];
    const float* W1_rc    = (const float*)d_in[12];
    const float* b1_rc    = (const float*)d_in[13];
    const float* W1_cr    = (const float*)d_in[14];
    const float* b1_cr    = (const float*)d_in[15];
    const int E = in_sizes[2];
    float* out = (float*)d_out;

    // workspace layout (~101 MB); partial hist (51.2 MB) aliases agg_col+agg_row (dead then)
    int*   cnt     = (int*)d_ws;                        // 200000
    float* norms   = (float*)(cnt + 200000);            // 200000 same order as cnt
    int*   ptr_rc  = (int*)(norms + 200000);            // 50004
    int*   ptr_cr  = ptr_rc + 50004;                    // 50004
    unsigned* pair_rc = (unsigned*)(ptr_cr + 50004);    // E (4-byte packed)
    unsigned* pair_cr = pair_rc + E;                    // E
    float* agg_col = (float*)(pair_cr + E);             // NCOL*128
    float* agg_row = agg_col + (size_t)NCOL * DH;       // NROW*128
    unsigned short* bf_row = (unsigned short*)(agg_row + (size_t)NROW * DH); // NROW*64
    unsigned short* bf_col = bf_row + (size_t)NROW * 64;                     // NCOL*64
    unsigned short* h_col1 = bf_col + (size_t)NCOL * 64;                     // NCOL*128
    unsigned short* h_row1 = h_col1 + (size_t)NCOL * DH;                     // NROW*128
    int*   partial = (int*)agg_col;                     // 16*HBLK*HB ints = 51.2 MB

    float* r_out_rc = norms;
    float* r_in_rc  = norms + NROW;
    float* r_out_cr = norms + NROW + NCOL;
    float* r_in_cr  = norms + NROW + 2 * NCOL;
    int*   c_in_rc  = cnt + NROW;
    int*   c_in_cr  = cnt + NROW + 2 * NCOL;

    // ---- CSR build (shared by both layers) + bf16 feature tables ----
    feats_to_bf16<<<2048, 256, 0, stream>>>((const float4*)feat_row, (const float4*)feat_col,
                                            (ushort4*)bf_row, (ushort4*)bf_col, NROW * 64 / 4);
    hist_lds<<<16 * HBLK, 512, 0, stream>>>(src_rc, dst_rc, src_cr, dst_cr, partial, E);
    reduce_norms2<<<512, 256, 0, stream>>>(partial, cnt, norms);
    excl_scan2<<<2, 1024, 0, stream>>>(c_in_rc, ptr_rc, NCOL, c_in_cr, ptr_cr, NROW);
    block_starts<<<400, 256, 0, stream>>>(partial, ptr_rc, ptr_cr);
    csr_fill_sorted<<<8 * HBLK, 512, 0, stream>>>(
        src_rc, dst_rc, w_rc, r_out_rc, pair_rc,
        src_cr, dst_cr, w_cr, r_out_cr, pair_cr, partial, E);

    // ---- layer 1 ----
    gather64_bf16<<<2048, 256, 0, stream>>>(bf_row, ptr_rc, pair_rc, agg_col, NCOL);
    dense_relu_k<64, false, true><<<2048, 128, 0, stream>>>(agg_col, r_in_rc, W0_rc, b0_rc, h_col1, NCOL, 0.f);
    gather64_bf16<<<2048, 256, 0, stream>>>(bf_col, ptr_cr, pair_cr, agg_row, NROW);
    dense_relu_k<64, false, true><<<2048, 128, 0, stream>>>(agg_row, r_in_cr, W0_cr, b0_cr, h_row1, NROW, 0.f);

    hipMemsetAsync(out, 0, DH * sizeof(float), stream);

    // ---- layer 2 + fused mean pooling ----
    gather128_bf16<<<2048, 256, 0, stream>>>(h_row1, ptr_rc, pair_rc, agg_col, NCOL);
    dense_relu_k<128, true, false><<<1024, 128, 0, stream>>>(agg_col, r_in_rc, W1_rc, b1_rc, out, NCOL, 1.0f / NCOL);
    gather128_bf16<<<2048, 256, 0, stream>>>(h_col1, ptr_cr, pair_cr, agg_row, NROW);
    dense_relu_k<128, true, false><<<1024, 128, 0, stream>>>(agg_row, r_in_cr, W1_cr, b1_cr, out, NROW, 1.0f / NROW);
}